// Round 1
// baseline (173.161 us; speedup 1.0000x reference)
//
#include <hip/hip_runtime.h>
#include <hip/hip_bf16.h>

// Problem constants
#define Bq 32
#define Lq 256
#define Hq 8
#define Eq 16
#define Nn (Bq*Hq)        // 256 sequences
#define T 254             // Lq - 3 + 1
#define A 145             // E + 1 + 128 augmented channels
#define SIG_CH (A + A*A)  // 21170
#define KP 21184          // padded K (mult of 32), bf16 arrays
#define OUT 256

typedef __attribute__((ext_vector_type(8))) short short8;
typedef __attribute__((ext_vector_type(8))) unsigned short ushort8;
typedef __attribute__((ext_vector_type(4))) float floatx4;

static __device__ __forceinline__ unsigned short f2bf(float v) {
    unsigned int u = __float_as_uint(v);
    unsigned int r = (u + 0x7FFFu + ((u >> 16) & 1u)) >> 16;
    return (unsigned short)r;
}
static __device__ __forceinline__ float bf2f(unsigned short b) {
    return __uint_as_float(((unsigned int)b) << 16);
}

// ---------------------------------------------------------------------------
// Kernel W+P merged: blocks 0..1323 = wconv (W -> wt_hi/lo transposed split);
// blocks 1324..1371 = wsplit (w1/w2 -> w1im/w2t bf16 split).
// ---------------------------------------------------------------------------
__global__ __launch_bounds__(256) void wprep_kernel(
    const float* __restrict__ W,
    unsigned short* __restrict__ wt_hi, unsigned short* __restrict__ wt_lo,
    const float* __restrict__ w1, const float* __restrict__ w2,
    unsigned short* __restrict__ w1im_hi, unsigned short* __restrict__ w1im_lo,
    unsigned short* __restrict__ w2t_hi,  unsigned short* __restrict__ w2t_lo)
{
    const int tid = threadIdx.x;
    if (blockIdx.x >= 1324) {
        int idx = (blockIdx.x - 1324)*256 + tid;   // 0..12287
        if (idx < 4096) {
            int c = idx & 63, k = idx >> 6;
            float v = (k < 48) ? w1[k*64 + c] : 0.f;
            unsigned short hb = f2bf(v);
            w1im_hi[c*64 + k] = hb;
            w1im_lo[c*64 + k] = f2bf(v - bf2f(hb));
        } else {
            int j = idx - 4096;
            int c = j & 127, i = j >> 7;
            float v = w2[i*128 + c];
            unsigned short hb = f2bf(v);
            w2t_hi[c*64 + i] = hb;
            w2t_lo[c*64 + i] = f2bf(v - bf2f(hb));
        }
        return;
    }

    __shared__ float ls[64][65];
    const int k0 = (blockIdx.x % 331) * 64;
    const int o0 = (blockIdx.x / 331) * 64;

    #pragma unroll
    for (int p = 0; p < 16; ++p) {
        int idx = tid + p*256;
        int kk = idx >> 6, oo = idx & 63;
        int k = k0 + kk;
        ls[kk][oo] = (k < SIG_CH) ? W[(long)k*OUT + o0 + oo] : 0.f;
    }
    __syncthreads();

    const int oo = tid >> 2;
    const int kq = (tid & 3) * 16;
    unsigned short hbuf[16], lbuf[16];
    #pragma unroll
    for (int j = 0; j < 16; ++j) {
        float v = ls[kq + j][oo];
        unsigned short hb = f2bf(v);
        hbuf[j] = hb;
        lbuf[j] = f2bf(v - bf2f(hb));
    }
    long off = (long)(o0 + oo)*KP + k0 + kq;
    *(ushort8*)(wt_hi + off)     = *(ushort8*)&hbuf[0];
    *(ushort8*)(wt_hi + off + 8) = *(ushort8*)&hbuf[8];
    *(ushort8*)(wt_lo + off)     = *(ushort8*)&lbuf[0];
    *(ushort8*)(wt_lo + off + 8) = *(ushort8*)&lbuf[8];
}

// ---------------------------------------------------------------------------
// Kernel AS: FUSED aug+sig. NOW 512 threads = 2 independent 4-wave chunk
// pipelines per block (group g handles chunks {g, g+2, g+4, g+6}).
// a0 is NOT subtracted in M anymore; exact rank-1 correction
// s2 -= a0_i * s1_j is applied in the fp32 epilogue (a0/vlast via LDS).
// Group 1 dumps its fp32 acc through (dead) pipeline LDS; group 0 sums,
// corrects, splits to bf16 and writes; group 1 writes s1 + zero-pad.
// ---------------------------------------------------------------------------
#define MDS 40    // M/D row stride (ushorts)
#define OS3 36    // outs row stride (floats)
#define XIS 72    // xim/a1 row stride (ushorts)
#define GRPB 61600 // per-group LDS bytes: 38400 (mdb) + 20880 (outs) + 2304 (xsc), padded

__global__ __launch_bounds__(512) void augsig_kernel(
    const float* __restrict__ q,
    const float* __restrict__ b1, const float* __restrict__ b2,
    const unsigned short* __restrict__ w1im_hi, const unsigned short* __restrict__ w1im_lo,
    const unsigned short* __restrict__ w2t_hi,  const unsigned short* __restrict__ w2t_lo,
    unsigned short* __restrict__ sig_hi, unsigned short* __restrict__ sig_lo)
{
    // 2*61600 + 256 (b1s) + 512 (b2s) + 640 (a0s) + 640 (vls) = 125248 B
    __shared__ __align__(16) char smem[2*GRPB + 256 + 512 + 640 + 640];

    const int tid512 = threadIdx.x;
    const int grp = tid512 >> 8;     // 0 or 1
    const int tid = tid512 & 255;    // local tid within group

    char* gb = smem + grp*GRPB;
    unsigned short* mdb = (unsigned short*)gb;          // 38400 B
    float* outs = (float*)(gb + 38400);                 // 20880 B
    float* xsc  = (float*)(gb + 59280);                 // 2304 B
    float* b1s  = (float*)(smem + 2*GRPB);              // 64 f
    float* b2s  = b1s + 64;                             // 128 f
    float* a0s  = b2s + 128;                            // 160 f (145 used)
    float* vls  = a0s + 160;                            // 160 f (145 used)
    float* accs = (float*)smem;  // 160*160 f = 102400 B, epilogue only (aliases dead pipeline LDS)

    unsigned short* Mh = mdb;
    unsigned short* Ml = mdb + 160*MDS;
    unsigned short* Dh = mdb + 2*160*MDS;
    unsigned short* ximh = mdb;
    unsigned short* ximl = mdb + 3456;
    unsigned short* a1h  = mdb + 6912;
    unsigned short* a1l  = mdb + 10368;

    const int n = blockIdx.x;
    const int b = n >> 3, h = n & 7;

    const int lane = tid & 63;
    const int wv   = tid >> 6;
    const int frow = lane & 15;
    const int quad = lane >> 4;
    const int wm = wv & 1, wn = wv >> 1;

    if (tid512 < 64)  b1s[tid512] = b1[tid512];
    if (tid512 < 128) b2s[tid512] = b2[tid512];

    const float4* q4 = (const float4*)q + ((long)(b*Lq)*Hq + h)*4;
    const float inv253 = 1.0f / 253.0f;

    floatx4 acc[5][5];
    #pragma unroll
    for (int i = 0; i < 5; ++i)
        #pragma unroll
        for (int j = 0; j < 5; ++j)
            acc[i][j] = (floatx4){0.f, 0.f, 0.f, 0.f};

    #pragma unroll 1
    for (int ci = 0; ci < 4; ++ci) {
        const int c = 2*ci + grp;
        const int t0 = c*32;

        if (tid < 140) {
            int r = tid >> 2, e4 = tid & 3;
            int t = t0 + r; if (t > 255) t = 255;
            *((float4*)xsc + (r*4 + e4)) = q4[t*32 + e4];
        }
        __syncthreads();   // B1

        for (int idx = tid; idx < 48*8; idx += 256) {
            int r = idx >> 3, g = idx & 7;
            unsigned short hh[8], ll[8];
            if (r <= 32 && g < 6) {
                const float* src = &xsc[r*16 + g*8];
                #pragma unroll
                for (int e = 0; e < 8; ++e) {
                    float v = src[e];
                    unsigned short hbv = f2bf(v);
                    hh[e] = hbv; ll[e] = f2bf(v - bf2f(hbv));
                }
            } else {
                #pragma unroll
                for (int e = 0; e < 8; ++e) { hh[e] = 0; ll[e] = 0; }
            }
            *(ushort8*)&ximh[r*XIS + g*8] = *(ushort8*)hh;
            *(ushort8*)&ximl[r*XIS + g*8] = *(ushort8*)ll;
        }
        __syncthreads();   // B2

        // conv1 MFMA
        {
            short8 ah[3][2], al[3][2];
            #pragma unroll
            for (int mt = 0; mt < 3; ++mt)
                #pragma unroll
                for (int ks = 0; ks < 2; ++ks) {
                    int ar = (mt*16 + frow)*XIS + ks*32 + quad*8;
                    ah[mt][ks] = *(const short8*)&ximh[ar];
                    al[mt][ks] = *(const short8*)&ximl[ar];
                }
            short8 bh[2], bl[2];
            #pragma unroll
            for (int ks = 0; ks < 2; ++ks) {
                int br = (wv*16 + frow)*64 + ks*32 + quad*8;
                bh[ks] = *(const short8*)(w1im_hi + br);
                bl[ks] = *(const short8*)(w1im_lo + br);
            }
            floatx4 acc1[3];
            #pragma unroll
            for (int mt = 0; mt < 3; ++mt) acc1[mt] = (floatx4){0.f,0.f,0.f,0.f};
            #pragma unroll
            for (int mt = 0; mt < 3; ++mt)
                #pragma unroll
                for (int ks = 0; ks < 2; ++ks) {
                    acc1[mt] = __builtin_amdgcn_mfma_f32_16x16x32_bf16(ah[mt][ks], bh[ks], acc1[mt], 0,0,0);
                    acc1[mt] = __builtin_amdgcn_mfma_f32_16x16x32_bf16(ah[mt][ks], bl[ks], acc1[mt], 0,0,0);
                    acc1[mt] = __builtin_amdgcn_mfma_f32_16x16x32_bf16(al[mt][ks], bh[ks], acc1[mt], 0,0,0);
                }
            const int cc = wv*16 + frow;
            const float bias = b1s[cc];
            #pragma unroll
            for (int mt = 0; mt < 3; ++mt)
                #pragma unroll
                for (int e = 0; e < 4; ++e) {
                    int t = mt*16 + quad*4 + e;
                    float v = acc1[mt][e] + bias;
                    unsigned short hbv = f2bf(v);
                    a1h[t*XIS + cc] = hbv;
                    a1l[t*XIS + cc] = f2bf(v - bf2f(hbv));
                }
        }
        __syncthreads();   // B3

        // conv2 MFMA
        {
            short8 ah[3][2], al[3][2];
            #pragma unroll
            for (int mt = 0; mt < 3; ++mt)
                #pragma unroll
                for (int ks = 0; ks < 2; ++ks) {
                    int ar = (mt*16 + frow)*XIS + ks*32 + quad*8;
                    ah[mt][ks] = *(const short8*)&a1h[ar];
                    al[mt][ks] = *(const short8*)&a1l[ar];
                }
            short8 bh[2][2], bl[2][2];
            #pragma unroll
            for (int nt = 0; nt < 2; ++nt)
                #pragma unroll
                for (int ks = 0; ks < 2; ++ks) {
                    int br = (wv*32 + nt*16 + frow)*64 + ks*32 + quad*8;
                    bh[nt][ks] = *(const short8*)(w2t_hi + br);
                    bl[nt][ks] = *(const short8*)(w2t_lo + br);
                }
            floatx4 acc2[3][2];
            #pragma unroll
            for (int mt = 0; mt < 3; ++mt)
                #pragma unroll
                for (int nt = 0; nt < 2; ++nt)
                    acc2[mt][nt] = (floatx4){0.f,0.f,0.f,0.f};
            #pragma unroll
            for (int mt = 0; mt < 3; ++mt)
                #pragma unroll
                for (int nt = 0; nt < 2; ++nt)
                    #pragma unroll
                    for (int ks = 0; ks < 2; ++ks) {
                        acc2[mt][nt] = __builtin_amdgcn_mfma_f32_16x16x32_bf16(ah[mt][ks], bh[nt][ks], acc2[mt][nt], 0,0,0);
                        acc2[mt][nt] = __builtin_amdgcn_mfma_f32_16x16x32_bf16(ah[mt][ks], bl[nt][ks], acc2[mt][nt], 0,0,0);
                        acc2[mt][nt] = __builtin_amdgcn_mfma_f32_16x16x32_bf16(al[mt][ks], bh[nt][ks], acc2[mt][nt], 0,0,0);
                    }
            #pragma unroll
            for (int mt = 0; mt < 3; ++mt)
                #pragma unroll
                for (int nt = 0; nt < 2; ++nt) {
                    int cc = wv*32 + nt*16 + frow;
                    float bias = b2s[cc];
                    int tb = mt*16 + quad*4;
                    if (tb <= 32) {
                        float4 vv;
                        vv.x = fmaxf(acc2[mt][nt][0] + bias, 0.f);
                        vv.y = fmaxf(acc2[mt][nt][1] + bias, 0.f);
                        vv.z = fmaxf(acc2[mt][nt][2] + bias, 0.f);
                        vv.w = fmaxf(acc2[mt][nt][3] + bias, 0.f);
                        *(float4*)&outs[(17 + cc)*OS3 + tb] = vv;
                    }
                }
        }
        for (int idx = tid; idx < 17*33; idx += 256) {
            int ch = idx / 33, tt = idx - ch*33;
            float val = (ch < 16) ? xsc[(tt+2)*16 + ch] : (float)(t0+tt)*inv253;
            outs[ch*OS3 + tt] = val;
        }
        __syncthreads();   // B4

        // M/D pack (M' = 0.5(x0+x1), NO a0 subtraction — corrected at epilogue)
        if (tid < 160) {
            unsigned short mh[32], ml[32], dh[32];
            if (tid < A) {
                float v[33];
                #pragma unroll
                for (int i = 0; i < 8; ++i)
                    *(float4*)&v[i*4] = *(const float4*)&outs[tid*OS3 + i*4];
                v[32] = outs[tid*OS3 + 32];
                if (c == 0) a0s[tid] = v[0];      // grp 0, first chunk
                if (c == 7) vls[tid] = v[29];     // grp 1, last chunk
                #pragma unroll
                for (int tl = 0; tl < 32; ++tl) {
                    bool valid = (t0 + tl) <= 252;
                    float x0 = v[tl], x1 = v[tl+1];
                    float d = valid ? (x1 - x0) : 0.f;
                    float m = valid ? (0.5f*(x0 + x1)) : 0.f;
                    unsigned short hbv = f2bf(m);
                    mh[tl] = hbv; ml[tl] = f2bf(m - bf2f(hbv));
                    dh[tl] = f2bf(d);
                }
            } else {
                #pragma unroll
                for (int tl = 0; tl < 32; ++tl) { mh[tl]=0; ml[tl]=0; dh[tl]=0; }
            }
            #pragma unroll
            for (int pp = 0; pp < 4; ++pp) {
                *(ushort8*)&Mh[tid*MDS + pp*8] = *(ushort8*)&mh[pp*8];
                *(ushort8*)&Ml[tid*MDS + pp*8] = *(ushort8*)&ml[pp*8];
                *(ushort8*)&Dh[tid*MDS + pp*8] = *(ushort8*)&dh[pp*8];
            }
        }
        __syncthreads();   // B5

        // signature MFMA
        {
            short8 afh[5], afl[5], bfh[5];
            #pragma unroll
            for (int i = 0; i < 5; ++i) {
                int ar = (wm*80 + i*16 + frow)*MDS + quad*8;
                int br = (wn*80 + i*16 + frow)*MDS + quad*8;
                afh[i] = *(const short8*)&Mh[ar];
                afl[i] = *(const short8*)&Ml[ar];
                bfh[i] = *(const short8*)&Dh[br];
            }
            #pragma unroll
            for (int mt = 0; mt < 5; ++mt)
                #pragma unroll
                for (int nt = 0; nt < 5; ++nt) {
                    acc[mt][nt] = __builtin_amdgcn_mfma_f32_16x16x32_bf16(
                        afh[mt], bfh[nt], acc[mt][nt], 0, 0, 0);
                    acc[mt][nt] = __builtin_amdgcn_mfma_f32_16x16x32_bf16(
                        afl[mt], bfh[nt], acc[mt][nt], 0, 0, 0);
                }
        }
    }

    // ----- epilogue: combine group accumulators, apply rank-1 correction -----
    __syncthreads();   // E1: all pipeline LDS dead; a0s/vls valid

    if (grp == 1) {
        #pragma unroll
        for (int mt = 0; mt < 5; ++mt)
            #pragma unroll
            for (int nt = 0; nt < 5; ++nt) {
                int j = wn*80 + nt*16 + frow;
                int ib = wm*80 + mt*16 + quad*4;
                #pragma unroll
                for (int e = 0; e < 4; ++e)
                    accs[(ib + e)*160 + j] = acc[mt][nt][e];
            }
    }
    __syncthreads();   // E2

    unsigned short* sh = sig_hi + (long)n*KP;
    unsigned short* sl = sig_lo + (long)n*KP;

    if (grp == 1) {
        // s1 + tail zero-pad (runs concurrently with grp0's big write)
        if (tid < A) {
            float v = vls[tid] - a0s[tid];
            unsigned short hbv = f2bf(v);
            sh[tid] = hbv;
            sl[tid] = f2bf(v - bf2f(hbv));
        }
        if (tid >= 160 && tid < 160 + (KP - SIG_CH)) {
            sh[SIG_CH + tid - 160] = 0;
            sl[SIG_CH + tid - 160] = 0;
        }
    } else {
        #pragma unroll
        for (int mt = 0; mt < 5; ++mt)
            #pragma unroll
            for (int nt = 0; nt < 5; ++nt) {
                int j = wn*80 + nt*16 + frow;
                int ib = wm*80 + mt*16 + quad*4;
                float s1j = (j < A) ? (vls[j] - a0s[j]) : 0.f;
                #pragma unroll
                for (int e = 0; e < 4; ++e) {
                    int i = ib + e;
                    if (i < A && j < A) {
                        float v = acc[mt][nt][e] + accs[i*160 + j] - a0s[i]*s1j;
                        unsigned short hbv = f2bf(v);
                        sh[A + i*A + j] = hbv;
                        sl[A + i*A + j] = f2bf(v - bf2f(hbv));
                    }
                }
            }
    }
}

// ---------------------------------------------------------------------------
// Kernel C: MFMA bf16 split GEMM, retiled 128n x 64o, grid (4,2,61) = 488
// blocks (~2/CU, LDS 30.7KB). Writes part; reduce adds bias.
// ---------------------------------------------------------------------------
#define SPLITK 61
#define KC 352
#define NSTEP (KC/32)   // 11
#define LDA 40

__global__ __launch_bounds__(256) void gemm_kernel(
    const unsigned short* __restrict__ sig_hi, const unsigned short* __restrict__ sig_lo,
    const unsigned short* __restrict__ wt_hi,  const unsigned short* __restrict__ wt_lo,
    float* __restrict__ part)
{
    __shared__ __align__(16) unsigned short Ah[128*LDA];
    __shared__ __align__(16) unsigned short Al[128*LDA];
    __shared__ __align__(16) unsigned short Bh[64*LDA];
    __shared__ __align__(16) unsigned short Bl[64*LDA];

    const int tid = threadIdx.x;
    const int o0 = blockIdx.x * 64;
    const int n0 = blockIdx.y * 128;
    const int z  = blockIdx.z;
    const int k0 = z * KC;

    const int lane = tid & 63;
    const int w    = tid >> 6;
    const int wm   = w & 1;          // n half (64 rows)
    const int wn   = w >> 1;         // o half (32 cols)
    const int frow = lane & 15;
    const int quad = lane >> 4;

    const int srowA = tid >> 1;
    const int khA   = (tid & 1) * 16;
    const int srowB = tid >> 2;
    const int kqB   = (tid & 3) * 8;

    const unsigned short* gAh = sig_hi + (long)(n0 + srowA)*KP;
    const unsigned short* gAl = sig_lo + (long)(n0 + srowA)*KP;
    const unsigned short* gBh = wt_hi  + (long)(o0 + srowB)*KP;
    const unsigned short* gBl = wt_lo  + (long)(o0 + srowB)*KP;

    ushort8 rah[2], ral[2], rbh, rbl;
    const ushort8 z8 = {0,0,0,0,0,0,0,0};

    #define GLOAD(s)                                                          \
        {                                                                     \
            int kb = k0 + (s)*32;                                             \
            if (kb < KP) {                                                    \
                rah[0] = *(const ushort8*)(gAh + kb + khA);                   \
                rah[1] = *(const ushort8*)(gAh + kb + khA + 8);               \
                ral[0] = *(const ushort8*)(gAl + kb + khA);                   \
                ral[1] = *(const ushort8*)(gAl + kb + khA + 8);               \
                rbh    = *(const ushort8*)(gBh + kb + kqB);                   \
                rbl    = *(const ushort8*)(gBl + kb + kqB);                   \
            } else {                                                          \
                rah[0]=z8; rah[1]=z8; ral[0]=z8; ral[1]=z8;                   \
                rbh=z8; rbl=z8;                                               \
            }                                                                 \
        }

    #define LSTORE()                                                          \
        {                                                                     \
            int oA = srowA*LDA + khA;                                         \
            *(ushort8*)(Ah + oA)     = rah[0];                                \
            *(ushort8*)(Ah + oA + 8) = rah[1];                                \
            *(ushort8*)(Al + oA)     = ral[0];                                \
            *(ushort8*)(Al + oA + 8) = ral[1];                                \
            int oB = srowB*LDA + kqB;                                         \
            *(ushort8*)(Bh + oB) = rbh;                                       \
            *(ushort8*)(Bl + oB) = rbl;                                       \
        }

    floatx4 acc[4][2];
    #pragma unroll
    for (int i = 0; i < 4; ++i)
        #pragma unroll
        for (int j = 0; j < 2; ++j)
            acc[i][j] = (floatx4){0.f, 0.f, 0.f, 0.f};

    GLOAD(0);
    LSTORE();
    __syncthreads();

    for (int s = 0; s < NSTEP; ++s) {
        if (s < NSTEP-1) GLOAD(s+1);

        short8 afh[4], afl[4], bfh[2], bfl[2];
        const int aoff = (wm*64 + frow)*LDA + quad*8;
        const int boff = (wn*32 + frow)*LDA + quad*8;
        #pragma unroll
        for (int tI = 0; tI < 4; ++tI) {
            afh[tI] = *(const short8*)(Ah + aoff + tI*16*LDA);
            afl[tI] = *(const short8*)(Al + aoff + tI*16*LDA);
        }
        #pragma unroll
        for (int tI = 0; tI < 2; ++tI) {
            bfh[tI] = *(const short8*)(Bh + boff + tI*16*LDA);
            bfl[tI] = *(const short8*)(Bl + boff + tI*16*LDA);
        }
        #pragma unroll
        for (int mt = 0; mt < 4; ++mt)
            #pragma unroll
            for (int nt = 0; nt < 2; ++nt) {
                acc[mt][nt] = __builtin_amdgcn_mfma_f32_16x16x32_bf16(
                    afh[mt], bfh[nt], acc[mt][nt], 0, 0, 0);
                acc[mt][nt] = __builtin_amdgcn_mfma_f32_16x16x32_bf16(
                    afh[mt], bfl[nt], acc[mt][nt], 0, 0, 0);
                acc[mt][nt] = __builtin_amdgcn_mfma_f32_16x16x32_bf16(
                    afl[mt], bfh[nt], acc[mt][nt], 0, 0, 0);
            }
        __syncthreads();
        if (s < NSTEP-1) {
            LSTORE();
            __syncthreads();
        }
    }

    float* pz = part + (long)z * (Nn*OUT);
    #pragma unroll
    for (int mt = 0; mt < 4; ++mt)
        #pragma unroll
        for (int nt = 0; nt < 2; ++nt) {
            int col = o0 + wn*32 + nt*16 + frow;
            int rbase = n0 + wm*64 + mt*16 + quad*4;
            #pragma unroll
            for (int e = 0; e < 4; ++e)
                pz[(long)(rbase + e)*OUT + col] = acc[mt][nt][e];
        }
}

// ---------------------------------------------------------------------------
// Kernel D: out[n][o] = lin_b[o] + sum_z part[z][n][o]
// ---------------------------------------------------------------------------
__global__ __launch_bounds__(256) void reduce_kernel(
    const float* __restrict__ part, const float* __restrict__ lb,
    float* __restrict__ out)
{
    int idx = blockIdx.x * 256 + threadIdx.x;
    float s = lb[idx & 255];
    #pragma unroll 8
    for (int z = 0; z < SPLITK; ++z)
        s += part[(long)z * (Nn*OUT) + idx];
    out[idx] = s;
}

// ---------------------------------------------------------------------------
extern "C" void kernel_launch(void* const* d_in, const int* in_sizes, int n_in,
                              void* d_out, int out_size, void* d_ws, size_t ws_size,
                              hipStream_t stream) {
    const float* q  = (const float*)d_in[0];
    const float* w1 = (const float*)d_in[4];
    const float* b1 = (const float*)d_in[5];
    const float* w2 = (const float*)d_in[6];
    const float* b2 = (const float*)d_in[7];
    const float* lw = (const float*)d_in[8];
    const float* lb = (const float*)d_in[9];
    float* out = (float*)d_out;

    // ws layout — 59.4 MB (proven envelope):
    //   [0]          sig_hi (10,846,208)
    //   [10846208]   sig_lo (10,846,208)
    //   [21692416]   wt_hi  (10,846,208)
    //   [32538624]   wt_lo  (10,846,208)
    //   [43384832]   part   (15,990,784)  ends 59,375,616
    //     w1im/w2t (48KB) live at part base until gemm overwrites (dead then)
    char* ws = (char*)d_ws;
    unsigned short* sig_hi  = (unsigned short*)ws;
    unsigned short* sig_lo  = (unsigned short*)(ws + 10846208);
    unsigned short* wt_hi   = (unsigned short*)(ws + 21692416);
    unsigned short* wt_lo   = (unsigned short*)(ws + 32538624);
    float*          part    = (float*)(ws + 43384832);
    unsigned short* w1im_hi = (unsigned short*)(ws + 43384832);
    unsigned short* w1im_lo = (unsigned short*)(ws + 43384832 + 8192);
    unsigned short* w2t_hi  = (unsigned short*)(ws + 43384832 + 16384);
    unsigned short* w2t_lo  = (unsigned short*)(ws + 43384832 + 32768);

    wprep_kernel<<<1372, 256, 0, stream>>>(lw, wt_hi, wt_lo,
                                           w1, w2, w1im_hi, w1im_lo, w2t_hi, w2t_lo);
    augsig_kernel<<<Nn, 512, 0, stream>>>(q, b1, b2, w1im_hi, w1im_lo, w2t_hi, w2t_lo, sig_hi, sig_lo);
    gemm_kernel<<<dim3(4, 2, SPLITK), 256, 0, stream>>>(sig_hi, sig_lo, wt_hi, wt_lo, part);
    reduce_kernel<<<(Nn*OUT)/256, 256, 0, stream>>>(part, lb, out);
}

// Round 2
// 157.568 us; speedup vs baseline: 1.0990x; 1.0990x over previous
//
#include <hip/hip_runtime.h>
#include <hip/hip_bf16.h>

// Problem constants
#define Bq 32
#define Lq 256
#define Hq 8
#define Eq 16
#define Nn (Bq*Hq)        // 256 sequences
#define T 254             // Lq - 3 + 1
#define A 145             // E + 1 + 128 augmented channels
#define SIG_CH (A + A*A)  // 21170
#define KP 21184          // padded K (mult of 32), bf16 arrays
#define OUT 256

typedef __attribute__((ext_vector_type(8))) short short8;
typedef __attribute__((ext_vector_type(8))) unsigned short ushort8;
typedef __attribute__((ext_vector_type(4))) float floatx4;

static __device__ __forceinline__ unsigned short f2bf(float v) {
    unsigned int u = __float_as_uint(v);
    unsigned int r = (u + 0x7FFFu + ((u >> 16) & 1u)) >> 16;
    return (unsigned short)r;
}
static __device__ __forceinline__ float bf2f(unsigned short b) {
    return __uint_as_float(((unsigned int)b) << 16);
}

// ---------------------------------------------------------------------------
// Kernel W+P merged: blocks 0..1323 = wconv (W -> wt_hi/lo transposed split);
// blocks 1324..1371 = wsplit (w1/w2 -> w1im/w2t bf16 split).
// ---------------------------------------------------------------------------
__global__ __launch_bounds__(256) void wprep_kernel(
    const float* __restrict__ W,
    unsigned short* __restrict__ wt_hi, unsigned short* __restrict__ wt_lo,
    const float* __restrict__ w1, const float* __restrict__ w2,
    unsigned short* __restrict__ w1im_hi, unsigned short* __restrict__ w1im_lo,
    unsigned short* __restrict__ w2t_hi,  unsigned short* __restrict__ w2t_lo)
{
    const int tid = threadIdx.x;
    if (blockIdx.x >= 1324) {
        int idx = (blockIdx.x - 1324)*256 + tid;   // 0..12287
        if (idx < 4096) {
            int c = idx & 63, k = idx >> 6;
            float v = (k < 48) ? w1[k*64 + c] : 0.f;
            unsigned short hb = f2bf(v);
            w1im_hi[c*64 + k] = hb;
            w1im_lo[c*64 + k] = f2bf(v - bf2f(hb));
        } else {
            int j = idx - 4096;
            int c = j & 127, i = j >> 7;
            float v = w2[i*128 + c];
            unsigned short hb = f2bf(v);
            w2t_hi[c*64 + i] = hb;
            w2t_lo[c*64 + i] = f2bf(v - bf2f(hb));
        }
        return;
    }

    __shared__ float ls[64][65];
    const int k0 = (blockIdx.x % 331) * 64;
    const int o0 = (blockIdx.x / 331) * 64;

    #pragma unroll
    for (int p = 0; p < 16; ++p) {
        int idx = tid + p*256;
        int kk = idx >> 6, oo = idx & 63;
        int k = k0 + kk;
        ls[kk][oo] = (k < SIG_CH) ? W[(long)k*OUT + o0 + oo] : 0.f;
    }
    __syncthreads();

    const int oo = tid >> 2;
    const int kq = (tid & 3) * 16;
    unsigned short hbuf[16], lbuf[16];
    #pragma unroll
    for (int j = 0; j < 16; ++j) {
        float v = ls[kq + j][oo];
        unsigned short hb = f2bf(v);
        hbuf[j] = hb;
        lbuf[j] = f2bf(v - bf2f(hb));
    }
    long off = (long)(o0 + oo)*KP + k0 + kq;
    *(ushort8*)(wt_hi + off)     = *(ushort8*)&hbuf[0];
    *(ushort8*)(wt_hi + off + 8) = *(ushort8*)&hbuf[8];
    *(ushort8*)(wt_lo + off)     = *(ushort8*)&lbuf[0];
    *(ushort8*)(wt_lo + off + 8) = *(ushort8*)&lbuf[8];
}

// ---------------------------------------------------------------------------
// Kernel AS: FUSED aug+sig. 512 threads = 2 independent 4-wave chunk
// pipelines per block (group g handles chunks {g, g+2, g+4, g+6}).
// a0 is NOT subtracted in M; exact rank-1 correction s2 -= a0_i*s1_j applied
// in fp32 at epilogue. This round: q prefetched to regs for all 4 chunks;
// M/D pack spread over 290 half-row tasks (no zero rows — junk rows only
// pollute discarded acc entries); epilogue stages corrected s2 in LDS and
// streams it with aligned ushort8 stores (kills partial-line write RMW).
// ---------------------------------------------------------------------------
#define MDS 40    // M/D row stride (ushorts)
#define OS3 36    // outs row stride (floats)
#define XIS 72    // xim/a1 row stride (ushorts)
#define GRPB 61600 // per-group LDS bytes

__global__ __launch_bounds__(512) void augsig_kernel(
    const float* __restrict__ q,
    const float* __restrict__ b1, const float* __restrict__ b2,
    const unsigned short* __restrict__ w1im_hi, const unsigned short* __restrict__ w1im_lo,
    const unsigned short* __restrict__ w2t_hi,  const unsigned short* __restrict__ w2t_lo,
    unsigned short* __restrict__ sig_hi, unsigned short* __restrict__ sig_lo)
{
    // 2*61600 + 256 (b1s) + 512 (b2s) + 640 (a0s) + 640 (vls) = 125248 B
    __shared__ __align__(16) char smem[2*GRPB + 256 + 512 + 640 + 640];

    const int tid512 = threadIdx.x;
    const int grp = tid512 >> 8;     // 0 or 1
    const int tid = tid512 & 255;    // local tid within group

    char* gb = smem + grp*GRPB;
    unsigned short* mdb = (unsigned short*)gb;          // 38400 B
    float* outs = (float*)(gb + 38400);                 // 20880 B
    float* xsc  = (float*)(gb + 59280);                 // 2304 B
    float* b1s  = (float*)(smem + 2*GRPB);              // 64 f
    float* b2s  = b1s + 64;                             // 128 f
    float* a0s  = b2s + 128;                            // 160 f (145 used)
    float* vls  = a0s + 160;                            // 160 f (145 used)
    float* accs = (float*)smem;  // 160*160 f = 102400 B, epilogue only (aliases dead pipeline LDS)

    unsigned short* Mh = mdb;
    unsigned short* Ml = mdb + 160*MDS;
    unsigned short* Dh = mdb + 2*160*MDS;
    unsigned short* ximh = mdb;
    unsigned short* ximl = mdb + 3456;
    unsigned short* a1h  = mdb + 6912;
    unsigned short* a1l  = mdb + 10368;

    const int n = blockIdx.x;
    const int b = n >> 3, h = n & 7;

    const int lane = tid & 63;
    const int wv   = tid >> 6;
    const int frow = lane & 15;
    const int quad = lane >> 4;
    const int wm = wv & 1, wn = wv >> 1;

    if (tid512 < 64)  b1s[tid512] = b1[tid512];
    if (tid512 < 128) b2s[tid512] = b2[tid512];

    const float4* q4 = (const float4*)q + ((long)(b*Lq)*Hq + h)*4;
    const float inv253 = 1.0f / 253.0f;

    // ---- q prefetch: all 4 chunks of this group into registers ----
    float4 rq0, rq1, rq2, rq3;
    if (tid < 140) {
        const int r = tid >> 2, e4 = tid & 3;
        int t;
        t = (0*2 + grp)*32 + r; if (t > 255) t = 255; rq0 = q4[t*32 + e4];
        t = (1*2 + grp)*32 + r; if (t > 255) t = 255; rq1 = q4[t*32 + e4];
        t = (2*2 + grp)*32 + r; if (t > 255) t = 255; rq2 = q4[t*32 + e4];
        t = (3*2 + grp)*32 + r; if (t > 255) t = 255; rq3 = q4[t*32 + e4];
    }

    floatx4 acc[5][5];
    #pragma unroll
    for (int i = 0; i < 5; ++i)
        #pragma unroll
        for (int j = 0; j < 5; ++j)
            acc[i][j] = (floatx4){0.f, 0.f, 0.f, 0.f};

    #pragma unroll 1
    for (int ci = 0; ci < 4; ++ci) {
        const int c = 2*ci + grp;
        const int t0 = c*32;

        if (tid < 140) {
            float4 qv = (ci == 0) ? rq0 : (ci == 1) ? rq1 : (ci == 2) ? rq2 : rq3;
            ((float4*)xsc)[tid] = qv;
        }
        __syncthreads();   // B1

        for (int idx = tid; idx < 48*8; idx += 256) {
            int r = idx >> 3, g = idx & 7;
            unsigned short hh[8], ll[8];
            if (r <= 32 && g < 6) {
                const float* src = &xsc[r*16 + g*8];
                #pragma unroll
                for (int e = 0; e < 8; ++e) {
                    float v = src[e];
                    unsigned short hbv = f2bf(v);
                    hh[e] = hbv; ll[e] = f2bf(v - bf2f(hbv));
                }
            } else {
                #pragma unroll
                for (int e = 0; e < 8; ++e) { hh[e] = 0; ll[e] = 0; }
            }
            *(ushort8*)&ximh[r*XIS + g*8] = *(ushort8*)hh;
            *(ushort8*)&ximl[r*XIS + g*8] = *(ushort8*)ll;
        }
        __syncthreads();   // B2

        // conv1 MFMA
        {
            short8 ah[3][2], al[3][2];
            #pragma unroll
            for (int mt = 0; mt < 3; ++mt)
                #pragma unroll
                for (int ks = 0; ks < 2; ++ks) {
                    int ar = (mt*16 + frow)*XIS + ks*32 + quad*8;
                    ah[mt][ks] = *(const short8*)&ximh[ar];
                    al[mt][ks] = *(const short8*)&ximl[ar];
                }
            short8 bh[2], bl[2];
            #pragma unroll
            for (int ks = 0; ks < 2; ++ks) {
                int br = (wv*16 + frow)*64 + ks*32 + quad*8;
                bh[ks] = *(const short8*)(w1im_hi + br);
                bl[ks] = *(const short8*)(w1im_lo + br);
            }
            floatx4 acc1[3];
            #pragma unroll
            for (int mt = 0; mt < 3; ++mt) acc1[mt] = (floatx4){0.f,0.f,0.f,0.f};
            #pragma unroll
            for (int mt = 0; mt < 3; ++mt)
                #pragma unroll
                for (int ks = 0; ks < 2; ++ks) {
                    acc1[mt] = __builtin_amdgcn_mfma_f32_16x16x32_bf16(ah[mt][ks], bh[ks], acc1[mt], 0,0,0);
                    acc1[mt] = __builtin_amdgcn_mfma_f32_16x16x32_bf16(ah[mt][ks], bl[ks], acc1[mt], 0,0,0);
                    acc1[mt] = __builtin_amdgcn_mfma_f32_16x16x32_bf16(al[mt][ks], bh[ks], acc1[mt], 0,0,0);
                }
            const int cc = wv*16 + frow;
            const float bias = b1s[cc];
            #pragma unroll
            for (int mt = 0; mt < 3; ++mt)
                #pragma unroll
                for (int e = 0; e < 4; ++e) {
                    int t = mt*16 + quad*4 + e;
                    float v = acc1[mt][e] + bias;
                    unsigned short hbv = f2bf(v);
                    a1h[t*XIS + cc] = hbv;
                    a1l[t*XIS + cc] = f2bf(v - bf2f(hbv));
                }
        }
        __syncthreads();   // B3

        // conv2 MFMA
        {
            short8 ah[3][2], al[3][2];
            #pragma unroll
            for (int mt = 0; mt < 3; ++mt)
                #pragma unroll
                for (int ks = 0; ks < 2; ++ks) {
                    int ar = (mt*16 + frow)*XIS + ks*32 + quad*8;
                    ah[mt][ks] = *(const short8*)&a1h[ar];
                    al[mt][ks] = *(const short8*)&a1l[ar];
                }
            short8 bh[2][2], bl[2][2];
            #pragma unroll
            for (int nt = 0; nt < 2; ++nt)
                #pragma unroll
                for (int ks = 0; ks < 2; ++ks) {
                    int br = (wv*32 + nt*16 + frow)*64 + ks*32 + quad*8;
                    bh[nt][ks] = *(const short8*)(w2t_hi + br);
                    bl[nt][ks] = *(const short8*)(w2t_lo + br);
                }
            floatx4 acc2[3][2];
            #pragma unroll
            for (int mt = 0; mt < 3; ++mt)
                #pragma unroll
                for (int nt = 0; nt < 2; ++nt)
                    acc2[mt][nt] = (floatx4){0.f,0.f,0.f,0.f};
            #pragma unroll
            for (int mt = 0; mt < 3; ++mt)
                #pragma unroll
                for (int nt = 0; nt < 2; ++nt)
                    #pragma unroll
                    for (int ks = 0; ks < 2; ++ks) {
                        acc2[mt][nt] = __builtin_amdgcn_mfma_f32_16x16x32_bf16(ah[mt][ks], bh[nt][ks], acc2[mt][nt], 0,0,0);
                        acc2[mt][nt] = __builtin_amdgcn_mfma_f32_16x16x32_bf16(ah[mt][ks], bl[nt][ks], acc2[mt][nt], 0,0,0);
                        acc2[mt][nt] = __builtin_amdgcn_mfma_f32_16x16x32_bf16(al[mt][ks], bh[nt][ks], acc2[mt][nt], 0,0,0);
                    }
            #pragma unroll
            for (int mt = 0; mt < 3; ++mt)
                #pragma unroll
                for (int nt = 0; nt < 2; ++nt) {
                    int cc = wv*32 + nt*16 + frow;
                    float bias = b2s[cc];
                    int tb = mt*16 + quad*4;
                    if (tb <= 32) {
                        float4 vv;
                        vv.x = fmaxf(acc2[mt][nt][0] + bias, 0.f);
                        vv.y = fmaxf(acc2[mt][nt][1] + bias, 0.f);
                        vv.z = fmaxf(acc2[mt][nt][2] + bias, 0.f);
                        vv.w = fmaxf(acc2[mt][nt][3] + bias, 0.f);
                        *(float4*)&outs[(17 + cc)*OS3 + tb] = vv;
                    }
                }
        }
        for (int idx = tid; idx < 17*33; idx += 256) {
            int ch = idx / 33, tt = idx - ch*33;
            float val = (ch < 16) ? xsc[(tt+2)*16 + ch] : (float)(t0+tt)*inv253;
            outs[ch*OS3 + tt] = val;
        }
        __syncthreads();   // B4

        // M/D pack: 290 half-row tasks over 256 threads (rows 145..159 left
        // as junk — they only feed acc entries with i>=145 or j>=145, never read)
        for (int task = tid; task < 290; task += 256) {
            int ch = task >> 1, hh2 = task & 1;
            const float* orow = &outs[ch*OS3 + hh2*16];
            float v[17];
            float4 va = *(const float4*)&orow[0];
            float4 vb = *(const float4*)&orow[4];
            float4 vc = *(const float4*)&orow[8];
            float4 vd = *(const float4*)&orow[12];
            v[0]=va.x; v[1]=va.y; v[2]=va.z; v[3]=va.w;
            v[4]=vb.x; v[5]=vb.y; v[6]=vb.z; v[7]=vb.w;
            v[8]=vc.x; v[9]=vc.y; v[10]=vc.z; v[11]=vc.w;
            v[12]=vd.x; v[13]=vd.y; v[14]=vd.z; v[15]=vd.w;
            v[16] = orow[16];
            if (c == 0 && hh2 == 0) a0s[ch] = v[0];      // grp 0, first chunk
            if (c == 7 && hh2 == 1) vls[ch] = v[13];     // grp 1, last chunk (global t idx 29)
            unsigned short mh[16], ml[16], dh[16];
            const int tbase = t0 + hh2*16;
            #pragma unroll
            for (int tl = 0; tl < 16; ++tl) {
                bool valid = (tbase + tl) <= 252;
                float x0 = v[tl], x1 = v[tl+1];
                float d = valid ? (x1 - x0) : 0.f;
                float m = valid ? (0.5f*(x0 + x1)) : 0.f;
                unsigned short hbv = f2bf(m);
                mh[tl] = hbv; ml[tl] = f2bf(m - bf2f(hbv));
                dh[tl] = f2bf(d);
            }
            int mo = ch*MDS + hh2*16;
            *(ushort8*)&Mh[mo]     = *(ushort8*)&mh[0];
            *(ushort8*)&Mh[mo + 8] = *(ushort8*)&mh[8];
            *(ushort8*)&Ml[mo]     = *(ushort8*)&ml[0];
            *(ushort8*)&Ml[mo + 8] = *(ushort8*)&ml[8];
            *(ushort8*)&Dh[mo]     = *(ushort8*)&dh[0];
            *(ushort8*)&Dh[mo + 8] = *(ushort8*)&dh[8];
        }
        __syncthreads();   // B5

        // signature MFMA
        {
            short8 afh[5], afl[5], bfh[5];
            #pragma unroll
            for (int i = 0; i < 5; ++i) {
                int ar = (wm*80 + i*16 + frow)*MDS + quad*8;
                int br = (wn*80 + i*16 + frow)*MDS + quad*8;
                afh[i] = *(const short8*)&Mh[ar];
                afl[i] = *(const short8*)&Ml[ar];
                bfh[i] = *(const short8*)&Dh[br];
            }
            #pragma unroll
            for (int mt = 0; mt < 5; ++mt)
                #pragma unroll
                for (int nt = 0; nt < 5; ++nt) {
                    acc[mt][nt] = __builtin_amdgcn_mfma_f32_16x16x32_bf16(
                        afh[mt], bfh[nt], acc[mt][nt], 0, 0, 0);
                    acc[mt][nt] = __builtin_amdgcn_mfma_f32_16x16x32_bf16(
                        afl[mt], bfh[nt], acc[mt][nt], 0, 0, 0);
                }
        }
    }

    // ----- epilogue -----
    __syncthreads();   // E1: all pipeline LDS dead; a0s/vls valid

    if (grp == 1) {
        #pragma unroll
        for (int mt = 0; mt < 5; ++mt)
            #pragma unroll
            for (int nt = 0; nt < 5; ++nt) {
                int j = wn*80 + nt*16 + frow;
                int ib = wm*80 + mt*16 + quad*4;
                #pragma unroll
                for (int e = 0; e < 4; ++e)
                    accs[(ib + e)*160 + j] = acc[mt][nt][e];
            }
    }
    __syncthreads();   // E2

    if (grp == 0) {
        // combine + rank-1 correction, staged back into accs (fp32)
        #pragma unroll
        for (int mt = 0; mt < 5; ++mt)
            #pragma unroll
            for (int nt = 0; nt < 5; ++nt) {
                int j = wn*80 + nt*16 + frow;
                int ib = wm*80 + mt*16 + quad*4;
                float s1j = (j < A) ? (vls[j] - a0s[j]) : 0.f;
                #pragma unroll
                for (int e = 0; e < 4; ++e) {
                    int i = ib + e;
                    float a0i = (i < A) ? a0s[i] : 0.f;
                    accs[i*160 + j] = acc[mt][nt][e] + accs[i*160 + j] - a0i*s1j;
                }
            }
    }
    __syncthreads();   // E3

    unsigned short* sh = sig_hi + (long)n*KP;
    unsigned short* sl = sig_lo + (long)n*KP;

    if (tid512 < 290) {
        // s2 rows: 2 threads per row, aligned ushort8 bulk + scalar edges
        const int r = tid512 >> 1, hh2 = tid512 & 1;
        const float* row = accs + r*160;
        const long g0 = (long)A + (long)r*A;      // ushort offset of row r
        const int s0 = (8 - (int)(g0 & 7)) & 7;   // scalars until 16B-aligned
        if (hh2 == 0) {
            for (int j = 0; j < s0; ++j) {
                float v = row[j];
                unsigned short hbv = f2bf(v);
                sh[g0 + j] = hbv;
                sl[g0 + j] = f2bf(v - bf2f(hbv));
            }
            for (int vb8 = 0; vb8 < 8; ++vb8) {
                int j0 = s0 + vb8*8;
                unsigned short hb8[8], lb8[8];
                #pragma unroll
                for (int e = 0; e < 8; ++e) {
                    float v = row[j0 + e];
                    unsigned short hbv = f2bf(v);
                    hb8[e] = hbv; lb8[e] = f2bf(v - bf2f(hbv));
                }
                *(ushort8*)(sh + g0 + j0) = *(ushort8*)hb8;
                *(ushort8*)(sl + g0 + j0) = *(ushort8*)lb8;
            }
        } else {
            int j0 = s0 + 64;
            for (; j0 + 8 <= A; j0 += 8) {
                unsigned short hb8[8], lb8[8];
                #pragma unroll
                for (int e = 0; e < 8; ++e) {
                    float v = row[j0 + e];
                    unsigned short hbv = f2bf(v);
                    hb8[e] = hbv; lb8[e] = f2bf(v - bf2f(hbv));
                }
                *(ushort8*)(sh + g0 + j0) = *(ushort8*)hb8;
                *(ushort8*)(sl + g0 + j0) = *(ushort8*)lb8;
            }
            for (; j0 < A; ++j0) {
                float v = row[j0];
                unsigned short hbv = f2bf(v);
                sh[g0 + j0] = hbv;
                sl[g0 + j0] = f2bf(v - bf2f(hbv));
            }
        }
    } else if (tid512 < 290 + A) {
        int ch = tid512 - 290;
        float v = vls[ch] - a0s[ch];
        unsigned short hbv = f2bf(v);
        sh[ch] = hbv;
        sl[ch] = f2bf(v - bf2f(hbv));
    } else if (tid512 < 290 + A + (KP - SIG_CH)) {
        int p = tid512 - (290 + A);
        sh[SIG_CH + p] = 0;
        sl[SIG_CH + p] = 0;
    }
}

// ---------------------------------------------------------------------------
// Kernel C: MFMA bf16 split GEMM, retiled 128n x 64o, grid (4,2,61) = 488
// blocks (~2/CU, LDS 30.7KB). XCD-swizzled so each z-slice's 8 blocks
// (720KB A+B working set) land on one XCD's L2. Writes part; reduce adds bias.
// ---------------------------------------------------------------------------
#define SPLITK 61
#define KC 352
#define NSTEP (KC/32)   // 11
#define LDA 40

__global__ __launch_bounds__(256) void gemm_kernel(
    const unsigned short* __restrict__ sig_hi, const unsigned short* __restrict__ sig_lo,
    const unsigned short* __restrict__ wt_hi,  const unsigned short* __restrict__ wt_lo,
    float* __restrict__ part)
{
    __shared__ __align__(16) unsigned short Ah[128*LDA];
    __shared__ __align__(16) unsigned short Al[128*LDA];
    __shared__ __align__(16) unsigned short Bh[64*LDA];
    __shared__ __align__(16) unsigned short Bl[64*LDA];

    const int tid = threadIdx.x;
    // XCD-aware bijective swizzle: dispatch-linear id -> (x,y,z) such that
    // all 8 blocks of one z-slice share an XCD (assumes XCD = linear % 8).
    const int lin  = blockIdx.x + 4*blockIdx.y + 8*blockIdx.z;   // 0..487
    const int lin2 = (lin & 7)*61 + (lin >> 3);                  // bijective
    const int z  = lin2 >> 3;
    const int m  = lin2 & 7;
    const int o0 = (m & 3) * 64;
    const int n0 = (m >> 2) * 128;
    const int k0 = z * KC;

    const int lane = tid & 63;
    const int w    = tid >> 6;
    const int wm   = w & 1;          // n half (64 rows)
    const int wn   = w >> 1;         // o half (32 cols)
    const int frow = lane & 15;
    const int quad = lane >> 4;

    const int srowA = tid >> 1;
    const int khA   = (tid & 1) * 16;
    const int srowB = tid >> 2;
    const int kqB   = (tid & 3) * 8;

    const unsigned short* gAh = sig_hi + (long)(n0 + srowA)*KP;
    const unsigned short* gAl = sig_lo + (long)(n0 + srowA)*KP;
    const unsigned short* gBh = wt_hi  + (long)(o0 + srowB)*KP;
    const unsigned short* gBl = wt_lo  + (long)(o0 + srowB)*KP;

    ushort8 rah[2], ral[2], rbh, rbl;
    const ushort8 z8 = {0,0,0,0,0,0,0,0};

    #define GLOAD(s)                                                          \
        {                                                                     \
            int kb = k0 + (s)*32;                                             \
            if (kb < KP) {                                                    \
                rah[0] = *(const ushort8*)(gAh + kb + khA);                   \
                rah[1] = *(const ushort8*)(gAh + kb + khA + 8);               \
                ral[0] = *(const ushort8*)(gAl + kb + khA);                   \
                ral[1] = *(const ushort8*)(gAl + kb + khA + 8);               \
                rbh    = *(const ushort8*)(gBh + kb + kqB);                   \
                rbl    = *(const ushort8*)(gBl + kb + kqB);                   \
            } else {                                                          \
                rah[0]=z8; rah[1]=z8; ral[0]=z8; ral[1]=z8;                   \
                rbh=z8; rbl=z8;                                               \
            }                                                                 \
        }

    #define LSTORE()                                                          \
        {                                                                     \
            int oA = srowA*LDA + khA;                                         \
            *(ushort8*)(Ah + oA)     = rah[0];                                \
            *(ushort8*)(Ah + oA + 8) = rah[1];                                \
            *(ushort8*)(Al + oA)     = ral[0];                                \
            *(ushort8*)(Al + oA + 8) = ral[1];                                \
            int oB = srowB*LDA + kqB;                                         \
            *(ushort8*)(Bh + oB) = rbh;                                       \
            *(ushort8*)(Bl + oB) = rbl;                                       \
        }

    floatx4 acc[4][2];
    #pragma unroll
    for (int i = 0; i < 4; ++i)
        #pragma unroll
        for (int j = 0; j < 2; ++j)
            acc[i][j] = (floatx4){0.f, 0.f, 0.f, 0.f};

    GLOAD(0);
    LSTORE();
    __syncthreads();

    for (int s = 0; s < NSTEP; ++s) {
        if (s < NSTEP-1) GLOAD(s+1);

        short8 afh[4], afl[4], bfh[2], bfl[2];
        const int aoff = (wm*64 + frow)*LDA + quad*8;
        const int boff = (wn*32 + frow)*LDA + quad*8;
        #pragma unroll
        for (int tI = 0; tI < 4; ++tI) {
            afh[tI] = *(const short8*)(Ah + aoff + tI*16*LDA);
            afl[tI] = *(const short8*)(Al + aoff + tI*16*LDA);
        }
        #pragma unroll
        for (int tI = 0; tI < 2; ++tI) {
            bfh[tI] = *(const short8*)(Bh + boff + tI*16*LDA);
            bfl[tI] = *(const short8*)(Bl + boff + tI*16*LDA);
        }
        #pragma unroll
        for (int mt = 0; mt < 4; ++mt)
            #pragma unroll
            for (int nt = 0; nt < 2; ++nt) {
                acc[mt][nt] = __builtin_amdgcn_mfma_f32_16x16x32_bf16(
                    afh[mt], bfh[nt], acc[mt][nt], 0, 0, 0);
                acc[mt][nt] = __builtin_amdgcn_mfma_f32_16x16x32_bf16(
                    afh[mt], bfl[nt], acc[mt][nt], 0, 0, 0);
                acc[mt][nt] = __builtin_amdgcn_mfma_f32_16x16x32_bf16(
                    afl[mt], bfh[nt], acc[mt][nt], 0, 0, 0);
            }
        __syncthreads();
        if (s < NSTEP-1) {
            LSTORE();
            __syncthreads();
        }
    }

    float* pz = part + (long)z * (Nn*OUT);
    #pragma unroll
    for (int mt = 0; mt < 4; ++mt)
        #pragma unroll
        for (int nt = 0; nt < 2; ++nt) {
            int col = o0 + wn*32 + nt*16 + frow;
            int rbase = n0 + wm*64 + mt*16 + quad*4;
            #pragma unroll
            for (int e = 0; e < 4; ++e)
                pz[(long)(rbase + e)*OUT + col] = acc[mt][nt][e];
        }
}

// ---------------------------------------------------------------------------
// Kernel D: out[n][o] = lin_b[o] + sum_z part[z][n][o]
// ---------------------------------------------------------------------------
__global__ __launch_bounds__(256) void reduce_kernel(
    const float* __restrict__ part, const float* __restrict__ lb,
    float* __restrict__ out)
{
    int idx = blockIdx.x * 256 + threadIdx.x;
    float s = lb[idx & 255];
    #pragma unroll 8
    for (int z = 0; z < SPLITK; ++z)
        s += part[(long)z * (Nn*OUT) + idx];
    out[idx] = s;
}

// ---------------------------------------------------------------------------
extern "C" void kernel_launch(void* const* d_in, const int* in_sizes, int n_in,
                              void* d_out, int out_size, void* d_ws, size_t ws_size,
                              hipStream_t stream) {
    const float* q  = (const float*)d_in[0];
    const float* w1 = (const float*)d_in[4];
    const float* b1 = (const float*)d_in[5];
    const float* w2 = (const float*)d_in[6];
    const float* b2 = (const float*)d_in[7];
    const float* lw = (const float*)d_in[8];
    const float* lb = (const float*)d_in[9];
    float* out = (float*)d_out;

    // ws layout — 59.4 MB (proven envelope):
    //   [0]          sig_hi (10,846,208)
    //   [10846208]   sig_lo (10,846,208)
    //   [21692416]   wt_hi  (10,846,208)
    //   [32538624]   wt_lo  (10,846,208)
    //   [43384832]   part   (15,990,784)  ends 59,375,616
    //     w1im/w2t (48KB) live at part base until gemm overwrites (dead then)
    char* ws = (char*)d_ws;
    unsigned short* sig_hi  = (unsigned short*)ws;
    unsigned short* sig_lo  = (unsigned short*)(ws + 10846208);
    unsigned short* wt_hi   = (unsigned short*)(ws + 21692416);
    unsigned short* wt_lo   = (unsigned short*)(ws + 32538624);
    float*          part    = (float*)(ws + 43384832);
    unsigned short* w1im_hi = (unsigned short*)(ws + 43384832);
    unsigned short* w1im_lo = (unsigned short*)(ws + 43384832 + 8192);
    unsigned short* w2t_hi  = (unsigned short*)(ws + 43384832 + 16384);
    unsigned short* w2t_lo  = (unsigned short*)(ws + 43384832 + 32768);

    wprep_kernel<<<1372, 256, 0, stream>>>(lw, wt_hi, wt_lo,
                                           w1, w2, w1im_hi, w1im_lo, w2t_hi, w2t_lo);
    augsig_kernel<<<Nn, 512, 0, stream>>>(q, b1, b2, w1im_hi, w1im_lo, w2t_hi, w2t_lo, sig_hi, sig_lo);
    gemm_kernel<<<dim3(4, 2, SPLITK), 256, 0, stream>>>(sig_hi, sig_lo, wt_hi, wt_lo, part);
    reduce_kernel<<<(Nn*OUT)/256, 256, 0, stream>>>(part, lb, out);
}

// Round 3
// 153.072 us; speedup vs baseline: 1.1312x; 1.0294x over previous
//
#include <hip/hip_runtime.h>
#include <hip/hip_bf16.h>

// Problem constants
#define Bq 32
#define Lq 256
#define Hq 8
#define Eq 16
#define Nn (Bq*Hq)        // 256 sequences
#define T 254             // Lq - 3 + 1
#define A 145             // E + 1 + 128 augmented channels
#define SIG_CH (A + A*A)  // 21170
#define KP 21184          // padded K (mult of 32), bf16 arrays
#define OUT 256

typedef __attribute__((ext_vector_type(8))) short short8;
typedef __attribute__((ext_vector_type(8))) unsigned short ushort8;
typedef __attribute__((ext_vector_type(4))) float floatx4;

static __device__ __forceinline__ unsigned short f2bf(float v) {
    unsigned int u = __float_as_uint(v);
    unsigned int r = (u + 0x7FFFu + ((u >> 16) & 1u)) >> 16;
    return (unsigned short)r;
}
static __device__ __forceinline__ float bf2f(unsigned short b) {
    return __uint_as_float(((unsigned int)b) << 16);
}

// ---------------------------------------------------------------------------
// Kernel W (small): w1/w2 -> w1im/w2t bf16 split. 48 blocks.
// (The big W->wt transpose pass is GONE: gemm reads W fp32 directly and
//  splits during LDS staging — bit-identical, saves 65 MB of HBM traffic.)
// ---------------------------------------------------------------------------
__global__ __launch_bounds__(256) void wprep_kernel(
    const float* __restrict__ w1, const float* __restrict__ w2,
    unsigned short* __restrict__ w1im_hi, unsigned short* __restrict__ w1im_lo,
    unsigned short* __restrict__ w2t_hi,  unsigned short* __restrict__ w2t_lo)
{
    int idx = blockIdx.x*256 + threadIdx.x;   // 0..12287
    if (idx < 4096) {
        int c = idx & 63, k = idx >> 6;
        float v = (k < 48) ? w1[k*64 + c] : 0.f;
        unsigned short hb = f2bf(v);
        w1im_hi[c*64 + k] = hb;
        w1im_lo[c*64 + k] = f2bf(v - bf2f(hb));
    } else {
        int j = idx - 4096;
        int c = j & 127, i = j >> 7;
        float v = w2[i*128 + c];
        unsigned short hb = f2bf(v);
        w2t_hi[c*64 + i] = hb;
        w2t_lo[c*64 + i] = f2bf(v - bf2f(hb));
    }
}

// ---------------------------------------------------------------------------
// Kernel AS: FUSED aug+sig. 512 threads = 2 chunk pipelines per block
// (group g handles chunks {g, g+2, g+4, g+6}). a0 deferred via rank-1
// correction at fp32 epilogue. accs stride 162 (was 160): 4*162 mod 32 = 8
// -> quads land 2-way per bank (free) instead of 4-way.
// ---------------------------------------------------------------------------
#define MDS 40    // M/D row stride (ushorts)
#define OS3 36    // outs row stride (floats)
#define XIS 72    // xim/a1 row stride (ushorts)
#define GRPB 61600 // per-group LDS bytes
#define ACS 162   // accs row stride (floats)

__global__ __launch_bounds__(512) void augsig_kernel(
    const float* __restrict__ q,
    const float* __restrict__ b1, const float* __restrict__ b2,
    const unsigned short* __restrict__ w1im_hi, const unsigned short* __restrict__ w1im_lo,
    const unsigned short* __restrict__ w2t_hi,  const unsigned short* __restrict__ w2t_lo,
    unsigned short* __restrict__ sig_hi, unsigned short* __restrict__ sig_lo)
{
    // 2*61600 + 256 (b1s) + 512 (b2s) + 640 (a0s) + 640 (vls) = 125248 B
    __shared__ __align__(16) char smem[2*GRPB + 256 + 512 + 640 + 640];

    const int tid512 = threadIdx.x;
    const int grp = tid512 >> 8;     // 0 or 1
    const int tid = tid512 & 255;    // local tid within group

    char* gb = smem + grp*GRPB;
    unsigned short* mdb = (unsigned short*)gb;          // 38400 B
    float* outs = (float*)(gb + 38400);                 // 20880 B
    float* xsc  = (float*)(gb + 59280);                 // 2304 B
    float* b1s  = (float*)(smem + 2*GRPB);              // 64 f
    float* b2s  = b1s + 64;                             // 128 f
    float* a0s  = b2s + 128;                            // 160 f (145 used)
    float* vls  = a0s + 160;                            // 160 f (145 used)
    float* accs = (float*)smem;  // 160*ACS*4 = 103,680 B, epilogue only (aliases dead pipeline LDS)

    unsigned short* Mh = mdb;
    unsigned short* Ml = mdb + 160*MDS;
    unsigned short* Dh = mdb + 2*160*MDS;
    unsigned short* ximh = mdb;
    unsigned short* ximl = mdb + 3456;
    unsigned short* a1h  = mdb + 6912;
    unsigned short* a1l  = mdb + 10368;

    const int n = blockIdx.x;
    const int b = n >> 3, h = n & 7;

    const int lane = tid & 63;
    const int wv   = tid >> 6;
    const int frow = lane & 15;
    const int quad = lane >> 4;
    const int wm = wv & 1, wn = wv >> 1;

    if (tid512 < 64)  b1s[tid512] = b1[tid512];
    if (tid512 < 128) b2s[tid512] = b2[tid512];

    const float4* q4 = (const float4*)q + ((long)(b*Lq)*Hq + h)*4;
    const float inv253 = 1.0f / 253.0f;

    // ---- q prefetch: all 4 chunks of this group into registers ----
    float4 rq0, rq1, rq2, rq3;
    if (tid < 140) {
        const int r = tid >> 2, e4 = tid & 3;
        int t;
        t = (0*2 + grp)*32 + r; if (t > 255) t = 255; rq0 = q4[t*32 + e4];
        t = (1*2 + grp)*32 + r; if (t > 255) t = 255; rq1 = q4[t*32 + e4];
        t = (2*2 + grp)*32 + r; if (t > 255) t = 255; rq2 = q4[t*32 + e4];
        t = (3*2 + grp)*32 + r; if (t > 255) t = 255; rq3 = q4[t*32 + e4];
    }

    floatx4 acc[5][5];
    #pragma unroll
    for (int i = 0; i < 5; ++i)
        #pragma unroll
        for (int j = 0; j < 5; ++j)
            acc[i][j] = (floatx4){0.f, 0.f, 0.f, 0.f};

    #pragma unroll 1
    for (int ci = 0; ci < 4; ++ci) {
        const int c = 2*ci + grp;
        const int t0 = c*32;

        if (tid < 140) {
            float4 qv = (ci == 0) ? rq0 : (ci == 1) ? rq1 : (ci == 2) ? rq2 : rq3;
            ((float4*)xsc)[tid] = qv;
        }
        __syncthreads();   // B1

        for (int idx = tid; idx < 48*8; idx += 256) {
            int r = idx >> 3, g = idx & 7;
            unsigned short hh[8], ll[8];
            if (r <= 32 && g < 6) {
                const float* src = &xsc[r*16 + g*8];
                #pragma unroll
                for (int e = 0; e < 8; ++e) {
                    float v = src[e];
                    unsigned short hbv = f2bf(v);
                    hh[e] = hbv; ll[e] = f2bf(v - bf2f(hbv));
                }
            } else {
                #pragma unroll
                for (int e = 0; e < 8; ++e) { hh[e] = 0; ll[e] = 0; }
            }
            *(ushort8*)&ximh[r*XIS + g*8] = *(ushort8*)hh;
            *(ushort8*)&ximl[r*XIS + g*8] = *(ushort8*)ll;
        }
        __syncthreads();   // B2

        // conv1 MFMA
        {
            short8 ah[3][2], al[3][2];
            #pragma unroll
            for (int mt = 0; mt < 3; ++mt)
                #pragma unroll
                for (int ks = 0; ks < 2; ++ks) {
                    int ar = (mt*16 + frow)*XIS + ks*32 + quad*8;
                    ah[mt][ks] = *(const short8*)&ximh[ar];
                    al[mt][ks] = *(const short8*)&ximl[ar];
                }
            short8 bh[2], bl[2];
            #pragma unroll
            for (int ks = 0; ks < 2; ++ks) {
                int br = (wv*16 + frow)*64 + ks*32 + quad*8;
                bh[ks] = *(const short8*)(w1im_hi + br);
                bl[ks] = *(const short8*)(w1im_lo + br);
            }
            floatx4 acc1[3];
            #pragma unroll
            for (int mt = 0; mt < 3; ++mt) acc1[mt] = (floatx4){0.f,0.f,0.f,0.f};
            #pragma unroll
            for (int mt = 0; mt < 3; ++mt)
                #pragma unroll
                for (int ks = 0; ks < 2; ++ks) {
                    acc1[mt] = __builtin_amdgcn_mfma_f32_16x16x32_bf16(ah[mt][ks], bh[ks], acc1[mt], 0,0,0);
                    acc1[mt] = __builtin_amdgcn_mfma_f32_16x16x32_bf16(ah[mt][ks], bl[ks], acc1[mt], 0,0,0);
                    acc1[mt] = __builtin_amdgcn_mfma_f32_16x16x32_bf16(al[mt][ks], bh[ks], acc1[mt], 0,0,0);
                }
            const int cc = wv*16 + frow;
            const float bias = b1s[cc];
            #pragma unroll
            for (int mt = 0; mt < 3; ++mt)
                #pragma unroll
                for (int e = 0; e < 4; ++e) {
                    int t = mt*16 + quad*4 + e;
                    float v = acc1[mt][e] + bias;
                    unsigned short hbv = f2bf(v);
                    a1h[t*XIS + cc] = hbv;
                    a1l[t*XIS + cc] = f2bf(v - bf2f(hbv));
                }
        }
        __syncthreads();   // B3

        // conv2 MFMA
        {
            short8 ah[3][2], al[3][2];
            #pragma unroll
            for (int mt = 0; mt < 3; ++mt)
                #pragma unroll
                for (int ks = 0; ks < 2; ++ks) {
                    int ar = (mt*16 + frow)*XIS + ks*32 + quad*8;
                    ah[mt][ks] = *(const short8*)&a1h[ar];
                    al[mt][ks] = *(const short8*)&a1l[ar];
                }
            short8 bh[2][2], bl[2][2];
            #pragma unroll
            for (int nt = 0; nt < 2; ++nt)
                #pragma unroll
                for (int ks = 0; ks < 2; ++ks) {
                    int br = (wv*32 + nt*16 + frow)*64 + ks*32 + quad*8;
                    bh[nt][ks] = *(const short8*)(w2t_hi + br);
                    bl[nt][ks] = *(const short8*)(w2t_lo + br);
                }
            floatx4 acc2[3][2];
            #pragma unroll
            for (int mt = 0; mt < 3; ++mt)
                #pragma unroll
                for (int nt = 0; nt < 2; ++nt)
                    acc2[mt][nt] = (floatx4){0.f,0.f,0.f,0.f};
            #pragma unroll
            for (int mt = 0; mt < 3; ++mt)
                #pragma unroll
                for (int nt = 0; nt < 2; ++nt)
                    #pragma unroll
                    for (int ks = 0; ks < 2; ++ks) {
                        acc2[mt][nt] = __builtin_amdgcn_mfma_f32_16x16x32_bf16(ah[mt][ks], bh[nt][ks], acc2[mt][nt], 0,0,0);
                        acc2[mt][nt] = __builtin_amdgcn_mfma_f32_16x16x32_bf16(ah[mt][ks], bl[nt][ks], acc2[mt][nt], 0,0,0);
                        acc2[mt][nt] = __builtin_amdgcn_mfma_f32_16x16x32_bf16(al[mt][ks], bh[nt][ks], acc2[mt][nt], 0,0,0);
                    }
            #pragma unroll
            for (int mt = 0; mt < 3; ++mt)
                #pragma unroll
                for (int nt = 0; nt < 2; ++nt) {
                    int cc = wv*32 + nt*16 + frow;
                    float bias = b2s[cc];
                    int tb = mt*16 + quad*4;
                    if (tb <= 32) {
                        float4 vv;
                        vv.x = fmaxf(acc2[mt][nt][0] + bias, 0.f);
                        vv.y = fmaxf(acc2[mt][nt][1] + bias, 0.f);
                        vv.z = fmaxf(acc2[mt][nt][2] + bias, 0.f);
                        vv.w = fmaxf(acc2[mt][nt][3] + bias, 0.f);
                        *(float4*)&outs[(17 + cc)*OS3 + tb] = vv;
                    }
                }
        }
        for (int idx = tid; idx < 17*33; idx += 256) {
            int ch = idx / 33, tt = idx - ch*33;
            float val = (ch < 16) ? xsc[(tt+2)*16 + ch] : (float)(t0+tt)*inv253;
            outs[ch*OS3 + tt] = val;
        }
        __syncthreads();   // B4

        // M/D pack: 290 half-row tasks over 256 threads
        for (int task = tid; task < 290; task += 256) {
            int ch = task >> 1, hh2 = task & 1;
            const float* orow = &outs[ch*OS3 + hh2*16];
            float v[17];
            float4 va = *(const float4*)&orow[0];
            float4 vb = *(const float4*)&orow[4];
            float4 vc = *(const float4*)&orow[8];
            float4 vd = *(const float4*)&orow[12];
            v[0]=va.x; v[1]=va.y; v[2]=va.z; v[3]=va.w;
            v[4]=vb.x; v[5]=vb.y; v[6]=vb.z; v[7]=vb.w;
            v[8]=vc.x; v[9]=vc.y; v[10]=vc.z; v[11]=vc.w;
            v[12]=vd.x; v[13]=vd.y; v[14]=vd.z; v[15]=vd.w;
            v[16] = orow[16];
            if (c == 0 && hh2 == 0) a0s[ch] = v[0];      // grp 0, first chunk
            if (c == 7 && hh2 == 1) vls[ch] = v[13];     // grp 1, last chunk (t=253)
            unsigned short mh[16], ml[16], dh[16];
            const int tbase = t0 + hh2*16;
            #pragma unroll
            for (int tl = 0; tl < 16; ++tl) {
                bool valid = (tbase + tl) <= 252;
                float x0 = v[tl], x1 = v[tl+1];
                float d = valid ? (x1 - x0) : 0.f;
                float m = valid ? (0.5f*(x0 + x1)) : 0.f;
                unsigned short hbv = f2bf(m);
                mh[tl] = hbv; ml[tl] = f2bf(m - bf2f(hbv));
                dh[tl] = f2bf(d);
            }
            int mo = ch*MDS + hh2*16;
            *(ushort8*)&Mh[mo]     = *(ushort8*)&mh[0];
            *(ushort8*)&Mh[mo + 8] = *(ushort8*)&mh[8];
            *(ushort8*)&Ml[mo]     = *(ushort8*)&ml[0];
            *(ushort8*)&Ml[mo + 8] = *(ushort8*)&ml[8];
            *(ushort8*)&Dh[mo]     = *(ushort8*)&dh[0];
            *(ushort8*)&Dh[mo + 8] = *(ushort8*)&dh[8];
        }
        __syncthreads();   // B5

        // signature MFMA
        {
            short8 afh[5], afl[5], bfh[5];
            #pragma unroll
            for (int i = 0; i < 5; ++i) {
                int ar = (wm*80 + i*16 + frow)*MDS + quad*8;
                int br = (wn*80 + i*16 + frow)*MDS + quad*8;
                afh[i] = *(const short8*)&Mh[ar];
                afl[i] = *(const short8*)&Ml[ar];
                bfh[i] = *(const short8*)&Dh[br];
            }
            #pragma unroll
            for (int mt = 0; mt < 5; ++mt)
                #pragma unroll
                for (int nt = 0; nt < 5; ++nt) {
                    acc[mt][nt] = __builtin_amdgcn_mfma_f32_16x16x32_bf16(
                        afh[mt], bfh[nt], acc[mt][nt], 0, 0, 0);
                    acc[mt][nt] = __builtin_amdgcn_mfma_f32_16x16x32_bf16(
                        afl[mt], bfh[nt], acc[mt][nt], 0, 0, 0);
                }
        }
    }

    // ----- epilogue -----
    __syncthreads();   // E1: all pipeline LDS dead; a0s/vls valid

    if (grp == 1) {
        #pragma unroll
        for (int mt = 0; mt < 5; ++mt)
            #pragma unroll
            for (int nt = 0; nt < 5; ++nt) {
                int j = wn*80 + nt*16 + frow;
                int ib = wm*80 + mt*16 + quad*4;
                #pragma unroll
                for (int e = 0; e < 4; ++e)
                    accs[(ib + e)*ACS + j] = acc[mt][nt][e];
            }
    }
    __syncthreads();   // E2

    if (grp == 0) {
        // combine + rank-1 correction, staged back into accs (fp32)
        #pragma unroll
        for (int mt = 0; mt < 5; ++mt)
            #pragma unroll
            for (int nt = 0; nt < 5; ++nt) {
                int j = wn*80 + nt*16 + frow;
                int ib = wm*80 + mt*16 + quad*4;
                float s1j = (j < A) ? (vls[j] - a0s[j]) : 0.f;
                #pragma unroll
                for (int e = 0; e < 4; ++e) {
                    int i = ib + e;
                    float a0i = (i < A) ? a0s[i] : 0.f;
                    accs[i*ACS + j] = acc[mt][nt][e] + accs[i*ACS + j] - a0i*s1j;
                }
            }
    }
    __syncthreads();   // E3

    unsigned short* sh = sig_hi + (long)n*KP;
    unsigned short* sl = sig_lo + (long)n*KP;

    if (tid512 < 290) {
        // s2 rows: 2 threads per row, aligned ushort8 bulk + scalar edges
        const int r = tid512 >> 1, hh2 = tid512 & 1;
        const float* row = accs + r*ACS;
        const long g0 = (long)A + (long)r*A;      // ushort offset of row r
        const int s0 = (8 - (int)(g0 & 7)) & 7;   // scalars until 16B-aligned
        if (hh2 == 0) {
            for (int j = 0; j < s0; ++j) {
                float v = row[j];
                unsigned short hbv = f2bf(v);
                sh[g0 + j] = hbv;
                sl[g0 + j] = f2bf(v - bf2f(hbv));
            }
            for (int vb8 = 0; vb8 < 8; ++vb8) {
                int j0 = s0 + vb8*8;
                unsigned short hb8[8], lb8[8];
                #pragma unroll
                for (int e = 0; e < 8; ++e) {
                    float v = row[j0 + e];
                    unsigned short hbv = f2bf(v);
                    hb8[e] = hbv; lb8[e] = f2bf(v - bf2f(hbv));
                }
                *(ushort8*)(sh + g0 + j0) = *(ushort8*)hb8;
                *(ushort8*)(sl + g0 + j0) = *(ushort8*)lb8;
            }
        } else {
            int j0 = s0 + 64;
            for (; j0 + 8 <= A; j0 += 8) {
                unsigned short hb8[8], lb8[8];
                #pragma unroll
                for (int e = 0; e < 8; ++e) {
                    float v = row[j0 + e];
                    unsigned short hbv = f2bf(v);
                    hb8[e] = hbv; lb8[e] = f2bf(v - bf2f(hbv));
                }
                *(ushort8*)(sh + g0 + j0) = *(ushort8*)hb8;
                *(ushort8*)(sl + g0 + j0) = *(ushort8*)lb8;
            }
            for (; j0 < A; ++j0) {
                float v = row[j0];
                unsigned short hbv = f2bf(v);
                sh[g0 + j0] = hbv;
                sl[g0 + j0] = f2bf(v - bf2f(hbv));
            }
        }
    } else if (tid512 < 290 + A) {
        int ch = tid512 - 290;
        float v = vls[ch] - a0s[ch];
        unsigned short hbv = f2bf(v);
        sh[ch] = hbv;
        sl[ch] = f2bf(v - bf2f(hbv));
    } else if (tid512 < 290 + A + (KP - SIG_CH)) {
        int p = tid512 - (290 + A);
        sh[SIG_CH + p] = 0;
        sl[SIG_CH + p] = 0;
    }
}

// ---------------------------------------------------------------------------
// Kernel C: MFMA bf16 split GEMM, 128n x 64o, grid (4,2,61), XCD-swizzled.
// B-operand now read DIRECTLY from W (fp32, [k][o] layout) and split to
// bf16 hi/lo in registers during LDS staging (bit-identical to the old
// precomputed wt path). Per-thread: 8 coalesced dword loads (lane = o).
// ---------------------------------------------------------------------------
#define SPLITK 61
#define KC 352
#define NSTEP (KC/32)   // 11
#define LDA 40

__global__ __launch_bounds__(256) void gemm_kernel(
    const unsigned short* __restrict__ sig_hi, const unsigned short* __restrict__ sig_lo,
    const float* __restrict__ W,
    float* __restrict__ part)
{
    __shared__ __align__(16) unsigned short Ah[128*LDA];
    __shared__ __align__(16) unsigned short Al[128*LDA];
    __shared__ __align__(16) unsigned short Bh[64*LDA];
    __shared__ __align__(16) unsigned short Bl[64*LDA];

    const int tid = threadIdx.x;
    // XCD-aware bijective swizzle: all 8 blocks of one z-slice share an XCD.
    const int lin  = blockIdx.x + 4*blockIdx.y + 8*blockIdx.z;   // 0..487
    const int lin2 = (lin & 7)*61 + (lin >> 3);                  // bijective
    const int z  = lin2 >> 3;
    const int m  = lin2 & 7;
    const int o0 = (m & 3) * 64;
    const int n0 = (m >> 2) * 128;
    const int k0 = z * KC;

    const int lane = tid & 63;
    const int w    = tid >> 6;
    const int wm   = w & 1;          // n half (64 rows)
    const int wn   = w >> 1;         // o half (32 cols)
    const int frow = lane & 15;
    const int quad = lane >> 4;

    const int srowA = tid >> 1;
    const int khA   = (tid & 1) * 16;
    const int oo    = tid & 63;      // B: o-offset (lane-contiguous -> coalesced)
    const int ks8   = tid >> 6;      // B: k-octet 0..3

    const unsigned short* gAh = sig_hi + (long)(n0 + srowA)*KP;
    const unsigned short* gAl = sig_lo + (long)(n0 + srowA)*KP;
    const float*          gB  = W + (o0 + oo);

    ushort8 rah[2], ral[2];
    float wv8[8];
    const ushort8 z8 = {0,0,0,0,0,0,0,0};

    #define GLOAD(s)                                                          \
        {                                                                     \
            int kb = k0 + (s)*32;                                             \
            if (kb < KP) {                                                    \
                rah[0] = *(const ushort8*)(gAh + kb + khA);                   \
                rah[1] = *(const ushort8*)(gAh + kb + khA + 8);               \
                ral[0] = *(const ushort8*)(gAl + kb + khA);                   \
                ral[1] = *(const ushort8*)(gAl + kb + khA + 8);               \
            } else {                                                          \
                rah[0]=z8; rah[1]=z8; ral[0]=z8; ral[1]=z8;                   \
            }                                                                 \
            int kbb = kb + ks8*8;                                             \
            _Pragma("unroll")                                                 \
            for (int j = 0; j < 8; ++j) {                                     \
                int k = kbb + j;                                              \
                wv8[j] = (k < SIG_CH) ? gB[(long)k*OUT] : 0.f;                \
            }                                                                 \
        }

    #define LSTORE()                                                          \
        {                                                                     \
            int oA = srowA*LDA + khA;                                         \
            *(ushort8*)(Ah + oA)     = rah[0];                                \
            *(ushort8*)(Ah + oA + 8) = rah[1];                                \
            *(ushort8*)(Al + oA)     = ral[0];                                \
            *(ushort8*)(Al + oA + 8) = ral[1];                                \
            unsigned short hb8[8], lb8[8];                                    \
            _Pragma("unroll")                                                 \
            for (int j = 0; j < 8; ++j) {                                     \
                unsigned short hbv = f2bf(wv8[j]);                            \
                hb8[j] = hbv; lb8[j] = f2bf(wv8[j] - bf2f(hbv));              \
            }                                                                 \
            int oB = oo*LDA + ks8*8;                                          \
            *(ushort8*)(Bh + oB) = *(ushort8*)hb8;                            \
            *(ushort8*)(Bl + oB) = *(ushort8*)lb8;                            \
        }

    floatx4 acc[4][2];
    #pragma unroll
    for (int i = 0; i < 4; ++i)
        #pragma unroll
        for (int j = 0; j < 2; ++j)
            acc[i][j] = (floatx4){0.f, 0.f, 0.f, 0.f};

    GLOAD(0);
    LSTORE();
    __syncthreads();

    for (int s = 0; s < NSTEP; ++s) {
        if (s < NSTEP-1) GLOAD(s+1);

        short8 afh[4], afl[4], bfh[2], bfl[2];
        const int aoff = (wm*64 + frow)*LDA + quad*8;
        const int boff = (wn*32 + frow)*LDA + quad*8;
        #pragma unroll
        for (int tI = 0; tI < 4; ++tI) {
            afh[tI] = *(const short8*)(Ah + aoff + tI*16*LDA);
            afl[tI] = *(const short8*)(Al + aoff + tI*16*LDA);
        }
        #pragma unroll
        for (int tI = 0; tI < 2; ++tI) {
            bfh[tI] = *(const short8*)(Bh + boff + tI*16*LDA);
            bfl[tI] = *(const short8*)(Bl + boff + tI*16*LDA);
        }
        #pragma unroll
        for (int mt = 0; mt < 4; ++mt)
            #pragma unroll
            for (int nt = 0; nt < 2; ++nt) {
                acc[mt][nt] = __builtin_amdgcn_mfma_f32_16x16x32_bf16(
                    afh[mt], bfh[nt], acc[mt][nt], 0, 0, 0);
                acc[mt][nt] = __builtin_amdgcn_mfma_f32_16x16x32_bf16(
                    afh[mt], bfl[nt], acc[mt][nt], 0, 0, 0);
                acc[mt][nt] = __builtin_amdgcn_mfma_f32_16x16x32_bf16(
                    afl[mt], bfh[nt], acc[mt][nt], 0, 0, 0);
            }
        __syncthreads();
        if (s < NSTEP-1) {
            LSTORE();
            __syncthreads();
        }
    }

    float* pz = part + (long)z * (Nn*OUT);
    #pragma unroll
    for (int mt = 0; mt < 4; ++mt)
        #pragma unroll
        for (int nt = 0; nt < 2; ++nt) {
            int col = o0 + wn*32 + nt*16 + frow;
            int rbase = n0 + wm*64 + mt*16 + quad*4;
            #pragma unroll
            for (int e = 0; e < 4; ++e)
                pz[(long)(rbase + e)*OUT + col] = acc[mt][nt][e];
        }
}

// ---------------------------------------------------------------------------
// Kernel D: out[n][o] = lin_b[o] + sum_z part[z][n][o]
// ---------------------------------------------------------------------------
__global__ __launch_bounds__(256) void reduce_kernel(
    const float* __restrict__ part, const float* __restrict__ lb,
    float* __restrict__ out)
{
    int idx = blockIdx.x * 256 + threadIdx.x;
    float s = lb[idx & 255];
    #pragma unroll 8
    for (int z = 0; z < SPLITK; ++z)
        s += part[(long)z * (Nn*OUT) + idx];
    out[idx] = s;
}

// ---------------------------------------------------------------------------
extern "C" void kernel_launch(void* const* d_in, const int* in_sizes, int n_in,
                              void* d_out, int out_size, void* d_ws, size_t ws_size,
                              hipStream_t stream) {
    const float* q  = (const float*)d_in[0];
    const float* w1 = (const float*)d_in[4];
    const float* b1 = (const float*)d_in[5];
    const float* w2 = (const float*)d_in[6];
    const float* b2 = (const float*)d_in[7];
    const float* lw = (const float*)d_in[8];
    const float* lb = (const float*)d_in[9];
    float* out = (float*)d_out;

    // ws layout (wt arrays dropped — gemm reads W directly):
    //   [0]          sig_hi (10,846,208)
    //   [10846208]   sig_lo (10,846,208)
    //   [43384832]   part   (15,990,784)  ends 59,375,616
    //     w1im/w2t (48KB) live at part base until gemm overwrites (dead then)
    char* ws = (char*)d_ws;
    unsigned short* sig_hi  = (unsigned short*)ws;
    unsigned short* sig_lo  = (unsigned short*)(ws + 10846208);
    float*          part    = (float*)(ws + 43384832);
    unsigned short* w1im_hi = (unsigned short*)(ws + 43384832);
    unsigned short* w1im_lo = (unsigned short*)(ws + 43384832 + 8192);
    unsigned short* w2t_hi  = (unsigned short*)(ws + 43384832 + 16384);
    unsigned short* w2t_lo  = (unsigned short*)(ws + 43384832 + 32768);

    wprep_kernel<<<48, 256, 0, stream>>>(w1, w2, w1im_hi, w1im_lo, w2t_hi, w2t_lo);
    augsig_kernel<<<Nn, 512, 0, stream>>>(q, b1, b2, w1im_hi, w1im_lo, w2t_hi, w2t_lo, sig_hi, sig_lo);
    gemm_kernel<<<dim3(4, 2, SPLITK), 256, 0, stream>>>(sig_hi, sig_lo, lw, part);
    reduce_kernel<<<(Nn*OUT)/256, 256, 0, stream>>>(part, lb, out);
}

// Round 4
// 152.204 us; speedup vs baseline: 1.1377x; 1.0057x over previous
//
#include <hip/hip_runtime.h>
#include <hip/hip_bf16.h>

// Problem constants
#define Bq 32
#define Lq 256
#define Hq 8
#define Eq 16
#define Nn (Bq*Hq)        // 256 sequences
#define T 254             // Lq - 3 + 1
#define A 145             // E + 1 + 128 augmented channels
#define SIG_CH (A + A*A)  // 21170
#define KP 21184          // padded K (mult of 32), bf16 arrays
#define OUT 256

typedef __attribute__((ext_vector_type(8))) short short8;
typedef __attribute__((ext_vector_type(8))) unsigned short ushort8;
typedef __attribute__((ext_vector_type(4))) float floatx4;

static __device__ __forceinline__ unsigned short f2bf(float v) {
    unsigned int u = __float_as_uint(v);
    unsigned int r = (u + 0x7FFFu + ((u >> 16) & 1u)) >> 16;
    return (unsigned short)r;
}
static __device__ __forceinline__ float bf2f(unsigned short b) {
    return __uint_as_float(((unsigned int)b) << 16);
}

// ---------------------------------------------------------------------------
// Kernel AS: FUSED aug+sig. 512 threads = 2 chunk pipelines per block
// (group g handles chunks {g, g+2, g+4, g+6}). a0 deferred via rank-1
// correction at fp32 epilogue.
// This round: (1) conv B-operands (w1/w2 bf16 hi/lo split) computed ONCE
// into registers at kernel start — wprep kernel deleted, no per-iter w VMEM.
// (2) im2col + outs-header read q DIRECTLY from global (L1/L2-hot) — the
// q->LDS(xsc) roundtrip and prefetch registers are gone.
// ---------------------------------------------------------------------------
#define MDS 40    // M/D row stride (ushorts)
#define OS3 36    // outs row stride (floats)
#define XIS 72    // xim/a1 row stride (ushorts)
#define GRPB 59280 // per-group LDS bytes: 38400 (mdb) + 20880 (outs)
#define ACS 162   // accs row stride (floats)

__global__ __launch_bounds__(512) void augsig_kernel(
    const float* __restrict__ q,
    const float* __restrict__ b1, const float* __restrict__ b2,
    const float* __restrict__ w1, const float* __restrict__ w2,
    unsigned short* __restrict__ sig_hi, unsigned short* __restrict__ sig_lo)
{
    // 2*59280 + 256 (b1s) + 512 (b2s) + 640 (a0s) + 640 (vls) = 120608 B
    __shared__ __align__(16) char smem[2*GRPB + 256 + 512 + 640 + 640];

    const int tid512 = threadIdx.x;
    const int grp = tid512 >> 8;     // 0 or 1
    const int tid = tid512 & 255;    // local tid within group

    char* gb = smem + grp*GRPB;
    unsigned short* mdb = (unsigned short*)gb;          // 38400 B
    float* outs = (float*)(gb + 38400);                 // 20880 B
    float* b1s  = (float*)(smem + 2*GRPB);              // 64 f
    float* b2s  = b1s + 64;                             // 128 f
    float* a0s  = b2s + 128;                            // 160 f (145 used)
    float* vls  = a0s + 160;                            // 160 f (145 used)
    float* accs = (float*)smem;  // 160*ACS*4 = 103,680 B, epilogue only (aliases dead pipeline LDS)

    unsigned short* Mh = mdb;
    unsigned short* Ml = mdb + 160*MDS;
    unsigned short* Dh = mdb + 2*160*MDS;
    unsigned short* ximh = mdb;
    unsigned short* ximl = mdb + 3456;
    unsigned short* a1h  = mdb + 6912;
    unsigned short* a1l  = mdb + 10368;

    const int n = blockIdx.x;
    const int b = n >> 3, h = n & 7;

    const int lane = tid & 63;
    const int wv   = tid >> 6;
    const int frow = lane & 15;
    const int quad = lane >> 4;
    const int wm = wv & 1, wn = wv >> 1;

    if (tid512 < 64)  b1s[tid512] = b1[tid512];
    if (tid512 < 128) b2s[tid512] = b2[tid512];

    const float4* q4 = (const float4*)q + ((long)(b*Lq)*Hq + h)*4;
    const float*  qf = q + ((long)(b*Lq)*Hq + h)*16;   // q[b][t][h][e] = qf[t*128+e]
    const float inv253 = 1.0f / 253.0f;

    // ---- conv B-operand fragments: computed once, held in registers ----
    // bit-identical to the old wprep path (same f2bf split).
    short8 c1bh[2], c1bl[2];
    {
        const int cch = wv*16 + frow;            // conv1 out-channel 0..63
        #pragma unroll
        for (int ks = 0; ks < 2; ++ks) {
            unsigned short hb8[8], lb8[8];
            #pragma unroll
            for (int e = 0; e < 8; ++e) {
                int k = ks*32 + quad*8 + e;      // im2col k 0..63 (48 real)
                float v = (k < 48) ? w1[k*64 + cch] : 0.f;
                unsigned short hbv = f2bf(v);
                hb8[e] = hbv; lb8[e] = f2bf(v - bf2f(hbv));
            }
            c1bh[ks] = *(short8*)hb8; c1bl[ks] = *(short8*)lb8;
        }
    }
    short8 c2bh[2][2], c2bl[2][2];
    #pragma unroll
    for (int nt = 0; nt < 2; ++nt) {
        const int cch = wv*32 + nt*16 + frow;    // conv2 out-channel 0..127
        #pragma unroll
        for (int ks = 0; ks < 2; ++ks) {
            unsigned short hb8[8], lb8[8];
            #pragma unroll
            for (int e = 0; e < 8; ++e) {
                int i = ks*32 + quad*8 + e;      // conv2 in-channel 0..63
                float v = w2[i*128 + cch];
                unsigned short hbv = f2bf(v);
                hb8[e] = hbv; lb8[e] = f2bf(v - bf2f(hbv));
            }
            c2bh[nt][ks] = *(short8*)hb8; c2bl[nt][ks] = *(short8*)lb8;
        }
    }

    floatx4 acc[5][5];
    #pragma unroll
    for (int i = 0; i < 5; ++i)
        #pragma unroll
        for (int j = 0; j < 5; ++j)
            acc[i][j] = (floatx4){0.f, 0.f, 0.f, 0.f};

    #pragma unroll 1
    for (int ci = 0; ci < 4; ++ci) {
        const int c = 2*ci + grp;
        const int t0 = c*32;

        __syncthreads();   // B1: previous sig-MFMA reads of mdb done before im2col writes

        // im2col pack, reading q directly (L1/L2-hot, 8 contiguous floats/task)
        for (int idx = tid; idx < 48*8; idx += 256) {
            int r = idx >> 3, g = idx & 7;
            unsigned short hh[8], ll[8];
            if (r <= 32 && g < 6) {
                int t = t0 + r + (g >> 1); if (t > 255) t = 255;
                float4 qa = q4[t*32 + (g&1)*2];
                float4 qb = q4[t*32 + (g&1)*2 + 1];
                float src[8] = {qa.x,qa.y,qa.z,qa.w, qb.x,qb.y,qb.z,qb.w};
                #pragma unroll
                for (int e = 0; e < 8; ++e) {
                    float v = src[e];
                    unsigned short hbv = f2bf(v);
                    hh[e] = hbv; ll[e] = f2bf(v - bf2f(hbv));
                }
            } else {
                #pragma unroll
                for (int e = 0; e < 8; ++e) { hh[e] = 0; ll[e] = 0; }
            }
            *(ushort8*)&ximh[r*XIS + g*8] = *(ushort8*)hh;
            *(ushort8*)&ximl[r*XIS + g*8] = *(ushort8*)ll;
        }
        __syncthreads();   // B2

        // conv1 MFMA
        {
            short8 ah[3][2], al[3][2];
            #pragma unroll
            for (int mt = 0; mt < 3; ++mt)
                #pragma unroll
                for (int ks = 0; ks < 2; ++ks) {
                    int ar = (mt*16 + frow)*XIS + ks*32 + quad*8;
                    ah[mt][ks] = *(const short8*)&ximh[ar];
                    al[mt][ks] = *(const short8*)&ximl[ar];
                }
            floatx4 acc1[3];
            #pragma unroll
            for (int mt = 0; mt < 3; ++mt) acc1[mt] = (floatx4){0.f,0.f,0.f,0.f};
            #pragma unroll
            for (int mt = 0; mt < 3; ++mt)
                #pragma unroll
                for (int ks = 0; ks < 2; ++ks) {
                    acc1[mt] = __builtin_amdgcn_mfma_f32_16x16x32_bf16(ah[mt][ks], c1bh[ks], acc1[mt], 0,0,0);
                    acc1[mt] = __builtin_amdgcn_mfma_f32_16x16x32_bf16(ah[mt][ks], c1bl[ks], acc1[mt], 0,0,0);
                    acc1[mt] = __builtin_amdgcn_mfma_f32_16x16x32_bf16(al[mt][ks], c1bh[ks], acc1[mt], 0,0,0);
                }
            const int cc = wv*16 + frow;
            const float bias = b1s[cc];
            #pragma unroll
            for (int mt = 0; mt < 3; ++mt)
                #pragma unroll
                for (int e = 0; e < 4; ++e) {
                    int t = mt*16 + quad*4 + e;
                    float v = acc1[mt][e] + bias;
                    unsigned short hbv = f2bf(v);
                    a1h[t*XIS + cc] = hbv;
                    a1l[t*XIS + cc] = f2bf(v - bf2f(hbv));
                }
        }
        __syncthreads();   // B3

        // conv2 MFMA
        {
            short8 ah[3][2], al[3][2];
            #pragma unroll
            for (int mt = 0; mt < 3; ++mt)
                #pragma unroll
                for (int ks = 0; ks < 2; ++ks) {
                    int ar = (mt*16 + frow)*XIS + ks*32 + quad*8;
                    ah[mt][ks] = *(const short8*)&a1h[ar];
                    al[mt][ks] = *(const short8*)&a1l[ar];
                }
            floatx4 acc2[3][2];
            #pragma unroll
            for (int mt = 0; mt < 3; ++mt)
                #pragma unroll
                for (int nt = 0; nt < 2; ++nt)
                    acc2[mt][nt] = (floatx4){0.f,0.f,0.f,0.f};
            #pragma unroll
            for (int mt = 0; mt < 3; ++mt)
                #pragma unroll
                for (int nt = 0; nt < 2; ++nt)
                    #pragma unroll
                    for (int ks = 0; ks < 2; ++ks) {
                        acc2[mt][nt] = __builtin_amdgcn_mfma_f32_16x16x32_bf16(ah[mt][ks], c2bh[nt][ks], acc2[mt][nt], 0,0,0);
                        acc2[mt][nt] = __builtin_amdgcn_mfma_f32_16x16x32_bf16(ah[mt][ks], c2bl[nt][ks], acc2[mt][nt], 0,0,0);
                        acc2[mt][nt] = __builtin_amdgcn_mfma_f32_16x16x32_bf16(al[mt][ks], c2bh[nt][ks], acc2[mt][nt], 0,0,0);
                    }
            #pragma unroll
            for (int mt = 0; mt < 3; ++mt)
                #pragma unroll
                for (int nt = 0; nt < 2; ++nt) {
                    int cc = wv*32 + nt*16 + frow;
                    float bias = b2s[cc];
                    int tb = mt*16 + quad*4;
                    if (tb <= 32) {
                        float4 vv;
                        vv.x = fmaxf(acc2[mt][nt][0] + bias, 0.f);
                        vv.y = fmaxf(acc2[mt][nt][1] + bias, 0.f);
                        vv.z = fmaxf(acc2[mt][nt][2] + bias, 0.f);
                        vv.w = fmaxf(acc2[mt][nt][3] + bias, 0.f);
                        *(float4*)&outs[(17 + cc)*OS3 + tb] = vv;
                    }
                }
        }
        // header rows: trunc (from q directly) + time channel
        for (int idx = tid; idx < 17*33; idx += 256) {
            int ch = idx / 33, tt = idx - ch*33;
            float val;
            if (ch < 16) {
                int t = t0 + tt + 2; if (t > 255) t = 255;
                val = qf[t*128 + ch];
            } else {
                val = (float)(t0+tt)*inv253;
            }
            outs[ch*OS3 + tt] = val;
        }
        __syncthreads();   // B4

        // M/D pack: 290 half-row tasks over 256 threads
        for (int task = tid; task < 290; task += 256) {
            int ch = task >> 1, hh2 = task & 1;
            const float* orow = &outs[ch*OS3 + hh2*16];
            float v[17];
            float4 va = *(const float4*)&orow[0];
            float4 vb = *(const float4*)&orow[4];
            float4 vc = *(const float4*)&orow[8];
            float4 vd = *(const float4*)&orow[12];
            v[0]=va.x; v[1]=va.y; v[2]=va.z; v[3]=va.w;
            v[4]=vb.x; v[5]=vb.y; v[6]=vb.z; v[7]=vb.w;
            v[8]=vc.x; v[9]=vc.y; v[10]=vc.z; v[11]=vc.w;
            v[12]=vd.x; v[13]=vd.y; v[14]=vd.z; v[15]=vd.w;
            v[16] = orow[16];
            if (c == 0 && hh2 == 0) a0s[ch] = v[0];      // grp 0, first chunk
            if (c == 7 && hh2 == 1) vls[ch] = v[13];     // grp 1, last chunk (t=253)
            unsigned short mh[16], ml[16], dh[16];
            const int tbase = t0 + hh2*16;
            #pragma unroll
            for (int tl = 0; tl < 16; ++tl) {
                bool valid = (tbase + tl) <= 252;
                float x0 = v[tl], x1 = v[tl+1];
                float d = valid ? (x1 - x0) : 0.f;
                float m = valid ? (0.5f*(x0 + x1)) : 0.f;
                unsigned short hbv = f2bf(m);
                mh[tl] = hbv; ml[tl] = f2bf(m - bf2f(hbv));
                dh[tl] = f2bf(d);
            }
            int mo = ch*MDS + hh2*16;
            *(ushort8*)&Mh[mo]     = *(ushort8*)&mh[0];
            *(ushort8*)&Mh[mo + 8] = *(ushort8*)&mh[8];
            *(ushort8*)&Ml[mo]     = *(ushort8*)&ml[0];
            *(ushort8*)&Ml[mo + 8] = *(ushort8*)&ml[8];
            *(ushort8*)&Dh[mo]     = *(ushort8*)&dh[0];
            *(ushort8*)&Dh[mo + 8] = *(ushort8*)&dh[8];
        }
        __syncthreads();   // B5

        // signature MFMA
        {
            short8 afh[5], afl[5], bfh[5];
            #pragma unroll
            for (int i = 0; i < 5; ++i) {
                int ar = (wm*80 + i*16 + frow)*MDS + quad*8;
                int br = (wn*80 + i*16 + frow)*MDS + quad*8;
                afh[i] = *(const short8*)&Mh[ar];
                afl[i] = *(const short8*)&Ml[ar];
                bfh[i] = *(const short8*)&Dh[br];
            }
            #pragma unroll
            for (int mt = 0; mt < 5; ++mt)
                #pragma unroll
                for (int nt = 0; nt < 5; ++nt) {
                    acc[mt][nt] = __builtin_amdgcn_mfma_f32_16x16x32_bf16(
                        afh[mt], bfh[nt], acc[mt][nt], 0, 0, 0);
                    acc[mt][nt] = __builtin_amdgcn_mfma_f32_16x16x32_bf16(
                        afl[mt], bfh[nt], acc[mt][nt], 0, 0, 0);
                }
        }
    }

    // ----- epilogue -----
    __syncthreads();   // E1: all pipeline LDS dead; a0s/vls valid

    if (grp == 1) {
        #pragma unroll
        for (int mt = 0; mt < 5; ++mt)
            #pragma unroll
            for (int nt = 0; nt < 5; ++nt) {
                int j = wn*80 + nt*16 + frow;
                int ib = wm*80 + mt*16 + quad*4;
                #pragma unroll
                for (int e = 0; e < 4; ++e)
                    accs[(ib + e)*ACS + j] = acc[mt][nt][e];
            }
    }
    __syncthreads();   // E2

    if (grp == 0) {
        // combine + rank-1 correction, staged back into accs (fp32)
        #pragma unroll
        for (int mt = 0; mt < 5; ++mt)
            #pragma unroll
            for (int nt = 0; nt < 5; ++nt) {
                int j = wn*80 + nt*16 + frow;
                int ib = wm*80 + mt*16 + quad*4;
                float s1j = (j < A) ? (vls[j] - a0s[j]) : 0.f;
                #pragma unroll
                for (int e = 0; e < 4; ++e) {
                    int i = ib + e;
                    float a0i = (i < A) ? a0s[i] : 0.f;
                    accs[i*ACS + j] = acc[mt][nt][e] + accs[i*ACS + j] - a0i*s1j;
                }
            }
    }
    __syncthreads();   // E3

    unsigned short* sh = sig_hi + (long)n*KP;
    unsigned short* sl = sig_lo + (long)n*KP;

    if (tid512 < 290) {
        // s2 rows: 2 threads per row, aligned ushort8 bulk + scalar edges
        const int r = tid512 >> 1, hh2 = tid512 & 1;
        const float* row = accs + r*ACS;
        const long g0 = (long)A + (long)r*A;      // ushort offset of row r
        const int s0 = (8 - (int)(g0 & 7)) & 7;   // scalars until 16B-aligned
        if (hh2 == 0) {
            for (int j = 0; j < s0; ++j) {
                float v = row[j];
                unsigned short hbv = f2bf(v);
                sh[g0 + j] = hbv;
                sl[g0 + j] = f2bf(v - bf2f(hbv));
            }
            for (int vb8 = 0; vb8 < 8; ++vb8) {
                int j0 = s0 + vb8*8;
                unsigned short hb8[8], lb8[8];
                #pragma unroll
                for (int e = 0; e < 8; ++e) {
                    float v = row[j0 + e];
                    unsigned short hbv = f2bf(v);
                    hb8[e] = hbv; lb8[e] = f2bf(v - bf2f(hbv));
                }
                *(ushort8*)(sh + g0 + j0) = *(ushort8*)hb8;
                *(ushort8*)(sl + g0 + j0) = *(ushort8*)lb8;
            }
        } else {
            int j0 = s0 + 64;
            for (; j0 + 8 <= A; j0 += 8) {
                unsigned short hb8[8], lb8[8];
                #pragma unroll
                for (int e = 0; e < 8; ++e) {
                    float v = row[j0 + e];
                    unsigned short hbv = f2bf(v);
                    hb8[e] = hbv; lb8[e] = f2bf(v - bf2f(hbv));
                }
                *(ushort8*)(sh + g0 + j0) = *(ushort8*)hb8;
                *(ushort8*)(sl + g0 + j0) = *(ushort8*)lb8;
            }
            for (; j0 < A; ++j0) {
                float v = row[j0];
                unsigned short hbv = f2bf(v);
                sh[g0 + j0] = hbv;
                sl[g0 + j0] = f2bf(v - bf2f(hbv));
            }
        }
    } else if (tid512 < 290 + A) {
        int ch = tid512 - 290;
        float v = vls[ch] - a0s[ch];
        unsigned short hbv = f2bf(v);
        sh[ch] = hbv;
        sl[ch] = f2bf(v - bf2f(hbv));
    } else if (tid512 < 290 + A + (KP - SIG_CH)) {
        int p = tid512 - (290 + A);
        sh[SIG_CH + p] = 0;
        sl[SIG_CH + p] = 0;
    }
}

// ---------------------------------------------------------------------------
// Kernel C: MFMA bf16 split GEMM, 128n x 64o, grid (4,2,61), XCD-swizzled.
// B-operand read DIRECTLY from W (fp32, [k][o] layout), split to bf16 hi/lo
// in registers during LDS staging.
// ---------------------------------------------------------------------------
#define SPLITK 61
#define KC 352
#define NSTEP (KC/32)   // 11
#define LDA 40

__global__ __launch_bounds__(256) void gemm_kernel(
    const unsigned short* __restrict__ sig_hi, const unsigned short* __restrict__ sig_lo,
    const float* __restrict__ W,
    float* __restrict__ part)
{
    __shared__ __align__(16) unsigned short Ah[128*LDA];
    __shared__ __align__(16) unsigned short Al[128*LDA];
    __shared__ __align__(16) unsigned short Bh[64*LDA];
    __shared__ __align__(16) unsigned short Bl[64*LDA];

    const int tid = threadIdx.x;
    // XCD-aware bijective swizzle: all 8 blocks of one z-slice share an XCD.
    const int lin  = blockIdx.x + 4*blockIdx.y + 8*blockIdx.z;   // 0..487
    const int lin2 = (lin & 7)*61 + (lin >> 3);                  // bijective
    const int z  = lin2 >> 3;
    const int m  = lin2 & 7;
    const int o0 = (m & 3) * 64;
    const int n0 = (m >> 2) * 128;
    const int k0 = z * KC;

    const int lane = tid & 63;
    const int w    = tid >> 6;
    const int wm   = w & 1;          // n half (64 rows)
    const int wn   = w >> 1;         // o half (32 cols)
    const int frow = lane & 15;
    const int quad = lane >> 4;

    const int srowA = tid >> 1;
    const int khA   = (tid & 1) * 16;
    const int oo    = tid & 63;      // B: o-offset (lane-contiguous -> coalesced)
    const int ks8   = tid >> 6;      // B: k-octet 0..3

    const unsigned short* gAh = sig_hi + (long)(n0 + srowA)*KP;
    const unsigned short* gAl = sig_lo + (long)(n0 + srowA)*KP;
    const float*          gB  = W + (o0 + oo);

    ushort8 rah[2], ral[2];
    float wv8[8];
    const ushort8 z8 = {0,0,0,0,0,0,0,0};

    #define GLOAD(s)                                                          \
        {                                                                     \
            int kb = k0 + (s)*32;                                             \
            if (kb < KP) {                                                    \
                rah[0] = *(const ushort8*)(gAh + kb + khA);                   \
                rah[1] = *(const ushort8*)(gAh + kb + khA + 8);               \
                ral[0] = *(const ushort8*)(gAl + kb + khA);                   \
                ral[1] = *(const ushort8*)(gAl + kb + khA + 8);               \
            } else {                                                          \
                rah[0]=z8; rah[1]=z8; ral[0]=z8; ral[1]=z8;                   \
            }                                                                 \
            int kbb = kb + ks8*8;                                             \
            _Pragma("unroll")                                                 \
            for (int j = 0; j < 8; ++j) {                                     \
                int k = kbb + j;                                              \
                wv8[j] = (k < SIG_CH) ? gB[(long)k*OUT] : 0.f;                \
            }                                                                 \
        }

    #define LSTORE()                                                          \
        {                                                                     \
            int oA = srowA*LDA + khA;                                         \
            *(ushort8*)(Ah + oA)     = rah[0];                                \
            *(ushort8*)(Ah + oA + 8) = rah[1];                                \
            *(ushort8*)(Al + oA)     = ral[0];                                \
            *(ushort8*)(Al + oA + 8) = ral[1];                                \
            unsigned short hb8[8], lb8[8];                                    \
            _Pragma("unroll")                                                 \
            for (int j = 0; j < 8; ++j) {                                     \
                unsigned short hbv = f2bf(wv8[j]);                            \
                hb8[j] = hbv; lb8[j] = f2bf(wv8[j] - bf2f(hbv));              \
            }                                                                 \
            int oB = oo*LDA + ks8*8;                                          \
            *(ushort8*)(Bh + oB) = *(ushort8*)hb8;                            \
            *(ushort8*)(Bl + oB) = *(ushort8*)lb8;                            \
        }

    floatx4 acc[4][2];
    #pragma unroll
    for (int i = 0; i < 4; ++i)
        #pragma unroll
        for (int j = 0; j < 2; ++j)
            acc[i][j] = (floatx4){0.f, 0.f, 0.f, 0.f};

    GLOAD(0);
    LSTORE();
    __syncthreads();

    for (int s = 0; s < NSTEP; ++s) {
        if (s < NSTEP-1) GLOAD(s+1);

        short8 afh[4], afl[4], bfh[2], bfl[2];
        const int aoff = (wm*64 + frow)*LDA + quad*8;
        const int boff = (wn*32 + frow)*LDA + quad*8;
        #pragma unroll
        for (int tI = 0; tI < 4; ++tI) {
            afh[tI] = *(const short8*)(Ah + aoff + tI*16*LDA);
            afl[tI] = *(const short8*)(Al + aoff + tI*16*LDA);
        }
        #pragma unroll
        for (int tI = 0; tI < 2; ++tI) {
            bfh[tI] = *(const short8*)(Bh + boff + tI*16*LDA);
            bfl[tI] = *(const short8*)(Bl + boff + tI*16*LDA);
        }
        #pragma unroll
        for (int mt = 0; mt < 4; ++mt)
            #pragma unroll
            for (int nt = 0; nt < 2; ++nt) {
                acc[mt][nt] = __builtin_amdgcn_mfma_f32_16x16x32_bf16(
                    afh[mt], bfh[nt], acc[mt][nt], 0, 0, 0);
                acc[mt][nt] = __builtin_amdgcn_mfma_f32_16x16x32_bf16(
                    afh[mt], bfl[nt], acc[mt][nt], 0, 0, 0);
                acc[mt][nt] = __builtin_amdgcn_mfma_f32_16x16x32_bf16(
                    afl[mt], bfh[nt], acc[mt][nt], 0, 0, 0);
            }
        __syncthreads();
        if (s < NSTEP-1) {
            LSTORE();
            __syncthreads();
        }
    }

    float* pz = part + (long)z * (Nn*OUT);
    #pragma unroll
    for (int mt = 0; mt < 4; ++mt)
        #pragma unroll
        for (int nt = 0; nt < 2; ++nt) {
            int col = o0 + wn*32 + nt*16 + frow;
            int rbase = n0 + wm*64 + mt*16 + quad*4;
            #pragma unroll
            for (int e = 0; e < 4; ++e)
                pz[(long)(rbase + e)*OUT + col] = acc[mt][nt][e];
        }
}

// ---------------------------------------------------------------------------
// Kernel D: out[n][o] = lin_b[o] + sum_z part[z][n][o]
// ---------------------------------------------------------------------------
__global__ __launch_bounds__(256) void reduce_kernel(
    const float* __restrict__ part, const float* __restrict__ lb,
    float* __restrict__ out)
{
    int idx = blockIdx.x * 256 + threadIdx.x;
    float s = lb[idx & 255];
    #pragma unroll 8
    for (int z = 0; z < SPLITK; ++z)
        s += part[(long)z * (Nn*OUT) + idx];
    out[idx] = s;
}

// ---------------------------------------------------------------------------
extern "C" void kernel_launch(void* const* d_in, const int* in_sizes, int n_in,
                              void* d_out, int out_size, void* d_ws, size_t ws_size,
                              hipStream_t stream) {
    const float* q  = (const float*)d_in[0];
    const float* w1 = (const float*)d_in[4];
    const float* b1 = (const float*)d_in[5];
    const float* w2 = (const float*)d_in[6];
    const float* b2 = (const float*)d_in[7];
    const float* lw = (const float*)d_in[8];
    const float* lb = (const float*)d_in[9];
    float* out = (float*)d_out;

    // ws layout:
    //   [0]          sig_hi (10,846,208)
    //   [10846208]   sig_lo (10,846,208)
    //   [43384832]   part   (15,990,784)  ends 59,375,616
    char* ws = (char*)d_ws;
    unsigned short* sig_hi  = (unsigned short*)ws;
    unsigned short* sig_lo  = (unsigned short*)(ws + 10846208);
    float*          part    = (float*)(ws + 43384832);

    augsig_kernel<<<Nn, 512, 0, stream>>>(q, b1, b2, w1, w2, sig_hi, sig_lo);
    gemm_kernel<<<dim3(4, 2, SPLITK), 256, 0, stream>>>(sig_hi, sig_lo, lw, part);
    reduce_kernel<<<(Nn*OUT)/256, 256, 0, stream>>>(part, lb, out);
}